// Round 6
// baseline (400.801 us; speedup 1.0000x reference)
//
#include <hip/hip_runtime.h>
#include <cstddef>
#include <cstdint>
#include <math.h>

typedef _Float16 f16;
typedef f16 f16x8 __attribute__((ext_vector_type(8)));
typedef f16 f16x4 __attribute__((ext_vector_type(4)));
typedef float f32x4 __attribute__((ext_vector_type(4)));

// ---------------- problem constants ----------------
constexpr int Bb   = 8;
constexpr int Ll   = 2048;
constexpr int Hin  = 128;
constexpr int Dm   = 512;
constexpr int Mrows = Bb * Ll;          // 16384
constexpr int NC   = 32;                // scan chunks per sequence
constexpr int CL   = Ll / NC;           // 64 timesteps per chunk
constexpr int SZ1  = Bb * NC * Dm;      // 131072 per state component
constexpr int SD   = 1024;              // interleaved [re|im] row stride

constexpr int TILE_ELE = 128 * 64;      // 128x64 f16 tile = 16 KB

// ---------------- device math helpers ----------------
static __device__ __forceinline__ float sigmoid_f(float x) {
    return 1.f / (1.f + expf(-x));
}
static __device__ __forceinline__ float gelu_tanh_f(float x) {
    float x3 = x * x * x;
    float t  = tanhf(0.7978845608028654f * (x + 0.044715f * x3));
    return 0.5f * x * (1.f + t);
}

// async global->LDS, 16 bytes per lane (linear LDS dest: wave base + lane*16)
static __device__ __forceinline__ void gld16(const f16* g, f16* l) {
    __builtin_amdgcn_global_load_lds(
        (const __attribute__((address_space(1))) void*)g,
        (__attribute__((address_space(3))) void*)l, 16, 0, 0);
}

// ---------------- weight-product fusion precompute ----------------
__global__ __launch_bounds__(128) void fuse_wc1(
    const float* __restrict__ Wenc, const float* __restrict__ Win,
    const float* __restrict__ b_in, const float* __restrict__ b_enc,
    f16* __restrict__ Wc1, float* __restrict__ bc1)
{
    const int d2 = blockIdx.x;      // 0..511
    const int t  = threadIdx.x;     // 0..127
    float acc = 0.f;
    for (int d = 0; d < Dm; ++d)
        acc = fmaf(Wenc[d2 * Dm + d], Win[d * Hin + t], acc);
    Wc1[d2 * Hin + t] = (f16)acc;
    if (t == 0) {
        float s = 0.f;
        for (int d = 0; d < Dm; ++d) s = fmaf(Wenc[d2 * Dm + d], b_in[d], s);
        bc1[d2] = s + b_enc[d2];
    }
}

__global__ __launch_bounds__(512) void fuse_wc2(
    const float* __restrict__ Wout, const float* __restrict__ Wdec,
    const float* __restrict__ b_dec, const float* __restrict__ b_out,
    f16* __restrict__ Wc2, float* __restrict__ bc2)
{
    const int o = blockIdx.x;   // 0..127
    const int t = threadIdx.x;  // 0..511
    float acc = 0.f;
    for (int d = 0; d < Dm; ++d)
        acc = fmaf(Wout[o * Dm + d], Wdec[d * Dm + t], acc);
    Wc2[o * Dm + t] = (f16)acc;
    if (t == 0) {
        float s = 0.f;
        for (int d = 0; d < Dm; ++d) s = fmaf(Wout[o * Dm + d], b_dec[d], s);
        bc2[o] = s + b_out[o];
    }
}

// ---------------- fp32 -> f16 conversion (pitched) ----------------
struct CvtJob { const float* s; f16* d; int n; int lgL; int pitch; int off; };
struct CvtJobs { CvtJob j[7]; };

__global__ __launch_bounds__(256) void convert_k(CvtJobs jobs) {
    const CvtJob jb = jobs.j[blockIdx.y];
    const int i = (blockIdx.x * 256 + threadIdx.x) * 4;
    if (i >= jb.n) return;
    const float4 v = *(const float4*)(jb.s + i);
    const int row = i >> jb.lgL;
    const int c   = i & ((1 << jb.lgL) - 1);
    f16x4 o;
    o.x = (f16)v.x; o.y = (f16)v.y; o.z = (f16)v.z; o.w = (f16)v.w;
    *(f16x4*)(jb.d + (size_t)row * jb.pitch + jb.off + c) = o;
}

// ---------------- fused MFMA GEMM (128x128 tile, BK=64, single-buffered) -----
// KM=0: C = A@W^T + bias
// KM=1: C = gelu( A@W^T + DV[col]*EX[row,col] )
// KM=4: A built on the fly: h2 = SK + P[:,0:512]*sigmoid(P[:,512:1024]); C = h2@W^T + bias
template <int KM, int OUTF16>
__global__ __launch_bounds__(256, (KM == 4) ? 2 : 5) void gemm_mfma(
    const f16* __restrict__ A, const f16* __restrict__ W,
    const float* __restrict__ bias,
    const f16* __restrict__ EX, const float* __restrict__ DV,
    const f16* __restrict__ SK,
    void* __restrict__ Cout, int M, int N, int K)
{
    __shared__ f16 smem[2 * TILE_ELE];  // As, Bs (32 KB)
    f16* As = smem;
    f16* Bs = smem + TILE_ELE;

    const int tid = threadIdx.x;
    const int l   = tid & 63;
    const int wid = tid >> 6;
    const int wr  = wid >> 1;
    const int wc  = wid & 1;
    const int lc  = l & 15;
    const int lr  = l >> 4;
    const int row0 = blockIdx.x * 128;
    const int col0 = blockIdx.y * 128;

    const int NT = K >> 6;
    const int swz  = (l & 7) << 4;
    const int off0 = ((lr * 16) ^ swz) >> 1;
    const int off1 = ((64 + lr * 16) ^ swz) >> 1;

    f32x4 acc[4][4];
#pragma unroll
    for (int i = 0; i < 4; ++i)
#pragma unroll
        for (int j = 0; j < 4; ++j) acc[i][j] = (f32x4){0.f, 0.f, 0.f, 0.f};

#define STAGE(DST, SRC, RS)                                                  \
    {                                                                        \
        _Pragma("unroll")                                                    \
        for (int c = 0; c < 4; ++c) {                                        \
            const int chunk = c * 256 + tid;                                 \
            const int row   = chunk >> 3;                                    \
            const int kb    = ((chunk & 7) << 4) ^ ((row & 7) << 4);         \
            gld16(SRC + (size_t)row * RS + (kb >> 1), DST + chunk * 8);      \
        }                                                                    \
    }

    for (int kt = 0; kt < NT; ++kt) {
        const int k0 = kt << 6;
        __syncthreads();
        if (KM == 4) {
            // reg-staged A: h2 = SK + P1*sigmoid(P2), written to linear LDS with
            // the same pre-swizzled source offsets as the gload path
#pragma unroll
            for (int c = 0; c < 4; ++c) {
                const int chunk = c * 256 + tid;
                const int row   = chunk >> 3;
                const int ke    = ((((chunk & 7) << 4) ^ ((row & 7) << 4)) >> 1);
                const size_t pb = (size_t)(row0 + row) * SD + k0 + ke;
                const f16x8 p1 = *(const f16x8*)(A + pb);
                const f16x8 p2 = *(const f16x8*)(A + pb + 512);
                const f16x8 sv = *(const f16x8*)(SK + (size_t)(row0 + row) * 512 + k0 + ke);
                f16x8 h;
#pragma unroll
                for (int j = 0; j < 8; ++j)
                    h[j] = (f16)((float)sv[j] + (float)p1[j] * sigmoid_f((float)p2[j]));
                *(f16x8*)(As + chunk * 8) = h;
            }
        } else {
            STAGE(As, A + (size_t)row0 * K + k0, K);
        }
        STAGE(Bs, W + (size_t)col0 * K + k0, K);
        __syncthreads();   // drains vmcnt/lgkmcnt -> tiles ready

#pragma unroll
        for (int ks = 0; ks < 2; ++ks) {
            const int off = ks ? off1 : off0;
            f16x8 aF[4], bF[4];
#pragma unroll
            for (int mi = 0; mi < 4; ++mi)
                aF[mi] = *(const f16x8*)(As + (wr * 64 + mi * 16 + lc) * 64 + off);
#pragma unroll
            for (int ni = 0; ni < 4; ++ni)
                bF[ni] = *(const f16x8*)(Bs + (wc * 64 + ni * 16 + lc) * 64 + off);
#pragma unroll
            for (int mi = 0; mi < 4; ++mi)
#pragma unroll
                for (int ni = 0; ni < 4; ++ni)
                    acc[mi][ni] = __builtin_amdgcn_mfma_f32_16x16x32_f16(
                        aF[mi], bF[ni], acc[mi][ni], 0, 0, 0);
        }
    }
#undef STAGE

    // ---------------- epilogue ----------------
    float* Cf32 = (float*)Cout;
    f16*   Cf16 = (f16*)Cout;
#pragma unroll
    for (int mi = 0; mi < 4; ++mi) {
#pragma unroll
        for (int ni = 0; ni < 4; ++ni) {
            const int col   = col0 + wc * 64 + ni * 16 + lc;
            const int rbase = row0 + wr * 64 + mi * 16 + lr * 4;
            const f32x4 v = acc[mi][ni];
            if (KM == 1) {
                const float dv = DV[col];
#pragma unroll
                for (int r = 0; r < 4; ++r) {
                    const size_t idx = (size_t)(rbase + r) * N + col;
                    const float o = gelu_tanh_f(v[r] + dv * (float)EX[idx]);
                    if (OUTF16) Cf16[idx] = (f16)o; else Cf32[idx] = o;
                }
            } else {
                const float bv = bias ? bias[col] : 0.f;
#pragma unroll
                for (int r = 0; r < 4; ++r) {
                    const float o = v[r] + bv;
                    const size_t idx = (size_t)(rbase + r) * N + col;
                    if (OUTF16) Cf16[idx] = (f16)o; else Cf32[idx] = o;
                }
            }
        }
    }
}

// ---------------- LayerNorm (rows of 512, f16 in/out) ----------------
__global__ __launch_bounds__(256) void layernorm_f16(
    const f16* __restrict__ X, const float* __restrict__ g,
    const float* __restrict__ b, f16* __restrict__ Y)
{
    const int lane = threadIdx.x & 63;
    const int w    = threadIdx.x >> 6;
    const int row  = blockIdx.x * 4 + w;
    const size_t base = (size_t)row * Dm + lane * 8;

    const f16x8 v = *(const f16x8*)(X + base);
    float x[8];
    float s = 0.f, q = 0.f;
#pragma unroll
    for (int i = 0; i < 8; ++i) {
        x[i] = (float)v[i];
        s += x[i]; q += x[i] * x[i];
    }
#pragma unroll
    for (int off = 32; off > 0; off >>= 1) {
        s += __shfl_xor(s, off);
        q += __shfl_xor(q, off);
    }
    const float mu  = s * (1.f / 512.f);
    const float var = q * (1.f / 512.f) - mu * mu;
    const float rs  = rsqrtf(var + 1e-5f);

    const float4 g0 = *(const float4*)(g + lane * 8);
    const float4 g1 = *(const float4*)(g + lane * 8 + 4);
    const float4 b0 = *(const float4*)(b + lane * 8);
    const float4 b1 = *(const float4*)(b + lane * 8 + 4);
    const float gg[8] = {g0.x, g0.y, g0.z, g0.w, g1.x, g1.y, g1.z, g1.w};
    const float bb[8] = {b0.x, b0.y, b0.z, b0.w, b1.x, b1.y, b1.z, b1.w};
    f16x8 o;
#pragma unroll
    for (int i = 0; i < 8; ++i)
        o[i] = (f16)((x[i] - mu) * rs * gg[i] + bb[i]);
    *(f16x8*)(Y + base) = o;
}

// ---------------- scan constants + concat GLU bias ----------------
__global__ void consts_k(const float* __restrict__ A_diag,
                         const float* __restrict__ log_steps,
                         const float* __restrict__ glu_b1,
                         const float* __restrict__ glu_b2,
                         float* __restrict__ cst, float* __restrict__ BG)
{
    const int n = threadIdx.x;
    const float a   = fmaxf(A_diag[n], 0.f);
    const float dt  = 1.f / (1.f + expf(-log_steps[n]));
    const float d2a = dt * dt * a;
    const float S   = 1.f / (1.f + d2a);
    const float m11 = 1.f - d2a * S;
    const float m12 = -dt * a * S;
    const float m21 = dt * S;
    const float m22 = S;
    cst[n]            = m11;
    cst[Dm + n]       = m12;
    cst[2 * Dm + n]   = m21;
    cst[3 * Dm + n]   = m22;
    cst[4 * Dm + n]   = m11 * dt;
    cst[5 * Dm + n]   = m21 * dt;
    BG[n]       = glu_b1[n];
    BG[Dm + n]  = glu_b2[n];
}

// ---------------- scan phase 1 (interleaved [re|im] rows of SD) --------------
__global__ __launch_bounds__(512) void scan_phase1(
    const f16* __restrict__ BU, const float* __restrict__ cst,
    float* __restrict__ S1)
{
    const int n = threadIdx.x;
    const int c = blockIdx.x & (NC - 1);
    const int b = blockIdx.x >> 5;
    const float m11 = cst[n],          m12 = cst[Dm + n];
    const float m21 = cst[2 * Dm + n], m22 = cst[3 * Dm + n];
    const float c1  = cst[4 * Dm + n], c2  = cst[5 * Dm + n];

    float zr = 0.f, xr = 0.f, zi = 0.f, xi = 0.f;
    const size_t base = ((size_t)b * Ll + (size_t)c * CL) * SD + n;
#pragma unroll 4
    for (int t = 0; t < CL; ++t) {
        const float br = (float)BU[base + (size_t)t * SD];
        const float bi = (float)BU[base + (size_t)t * SD + 512];
        const float zrn = fmaf(m11, zr, fmaf(m12, xr, c1 * br));
        const float xrn = fmaf(m21, zr, fmaf(m22, xr, c2 * br));
        const float zin = fmaf(m11, zi, fmaf(m12, xi, c1 * bi));
        const float xin = fmaf(m21, zi, fmaf(m22, xi, c2 * bi));
        zr = zrn; xr = xrn; zi = zin; xi = xin;
    }
    const int idx = blockIdx.x * Dm + n;
    S1[idx]            = zr;
    S1[SZ1 + idx]      = xr;
    S1[2 * SZ1 + idx]  = zi;
    S1[3 * SZ1 + idx]  = xi;
}

// ---------------- scan phase 2 ----------------
__global__ __launch_bounds__(256) void scan_phase2(
    const float* __restrict__ S1, const float* __restrict__ cst,
    float* __restrict__ G)
{
    const int gidx = blockIdx.x * 256 + threadIdx.x; // 0..4095
    const int n = gidx & (Dm - 1);
    const int b = gidx >> 9;
    const float m11 = cst[n],          m12 = cst[Dm + n];
    const float m21 = cst[2 * Dm + n], m22 = cst[3 * Dm + n];

    float p11 = 1.f, p12 = 0.f, p21 = 0.f, p22 = 1.f;
    for (int i = 0; i < CL; ++i) {
        const float q11 = m11 * p11 + m12 * p21;
        const float q12 = m11 * p12 + m12 * p22;
        const float q21 = m21 * p11 + m22 * p21;
        const float q22 = m21 * p12 + m22 * p22;
        p11 = q11; p12 = q12; p21 = q21; p22 = q22;
    }

    float gzr = 0.f, gxr = 0.f, gzi = 0.f, gxi = 0.f;
    for (int c = 0; c < NC; ++c) {
        const int idx = (b * NC + c) * Dm + n;
        G[idx]           = gzr;
        G[SZ1 + idx]     = gxr;
        G[2 * SZ1 + idx] = gzi;
        G[3 * SZ1 + idx] = gxi;
        const float szr = S1[idx],           sxr = S1[SZ1 + idx];
        const float szi = S1[2 * SZ1 + idx], sxi = S1[3 * SZ1 + idx];
        const float t1 = p11 * gzr + p12 * gxr + szr;
        const float t2 = p21 * gzr + p22 * gxr + sxr;
        const float t3 = p11 * gzi + p12 * gxi + szi;
        const float t4 = p21 * gzi + p22 * gxi + sxi;
        gzr = t1; gxr = t2; gzi = t3; gxi = t4;
    }
}

// ---------------- scan phase 3: re-scan; XS = [xr | -xi] interleaved ---------
__global__ __launch_bounds__(512) void scan_phase3(
    const f16* __restrict__ BU, const float* __restrict__ cst,
    const float* __restrict__ G, f16* __restrict__ XS)
{
    const int n = threadIdx.x;
    const int c = blockIdx.x & (NC - 1);
    const int b = blockIdx.x >> 5;
    const float m11 = cst[n],          m12 = cst[Dm + n];
    const float m21 = cst[2 * Dm + n], m22 = cst[3 * Dm + n];
    const float c1  = cst[4 * Dm + n], c2  = cst[5 * Dm + n];

    const int sidx = blockIdx.x * Dm + n;
    float zr = G[sidx];
    float xr = G[SZ1 + sidx];
    float zi = G[2 * SZ1 + sidx];
    float xi = G[3 * SZ1 + sidx];

    const size_t base = ((size_t)b * Ll + (size_t)c * CL) * SD + n;
#pragma unroll 4
    for (int t = 0; t < CL; ++t) {
        const float br = (float)BU[base + (size_t)t * SD];
        const float bi = (float)BU[base + (size_t)t * SD + 512];
        const float zrn = fmaf(m11, zr, fmaf(m12, xr, c1 * br));
        const float xrn = fmaf(m21, zr, fmaf(m22, xr, c2 * br));
        const float zin = fmaf(m11, zi, fmaf(m12, xi, c1 * bi));
        const float xin = fmaf(m21, zi, fmaf(m22, xi, c2 * bi));
        zr = zrn; xr = xrn; zi = zin; xi = xin;
        XS[base + (size_t)t * SD]       = (f16)xr;
        XS[base + (size_t)t * SD + 512] = (f16)(-xi);
    }
}

// ---------------- launch ----------------
extern "C" void kernel_launch(void* const* d_in, const int* in_sizes, int n_in,
                              void* d_out, int out_size, void* d_ws, size_t ws_size,
                              hipStream_t stream)
{
    const float* x         = (const float*)d_in[0];
    const float* W_in      = (const float*)d_in[1];
    const float* b_in      = (const float*)d_in[2];
    const float* W_enc     = (const float*)d_in[3];
    const float* b_enc     = (const float*)d_in[4];
    const float* ln_g      = (const float*)d_in[5];
    const float* ln_b      = (const float*)d_in[6];
    const float* A_diag    = (const float*)d_in[7];
    const float* log_steps = (const float*)d_in[8];
    const float* B_re      = (const float*)d_in[9];
    const float* B_im      = (const float*)d_in[10];
    const float* C_re      = (const float*)d_in[11];
    const float* C_im      = (const float*)d_in[12];
    const float* Dv        = (const float*)d_in[13];
    const float* glu_w1    = (const float*)d_in[14];
    const float* glu_b1    = (const float*)d_in[15];
    const float* glu_w2    = (const float*)d_in[16];
    const float* glu_b2    = (const float*)d_in[17];
    const float* W_dec     = (const float*)d_in[18];
    const float* b_dec     = (const float*)d_in[19];
    const float* W_out     = (const float*)d_in[20];
    const float* b_out     = (const float*)d_in[21];

    char* ws = (char*)d_ws;
    const size_t MB = 1 << 20;
    f16*   F2  = (f16*)(ws);             // skip f16 [M,512]
    f16*   F3  = (f16*)(ws + 16 * MB);   // hn f16 [M,512]
    f16*   XS  = (f16*)(ws + 32 * MB);   // [M,1024] = [xr | -xi]
    f16*   BU  = (f16*)(ws + 64 * MB);   // [M,1024] = [BuR | BuI]; later P
    f16*   Pp  = BU;                     // P aliases BU (dead after phase3)
    f16*   GF  = (f16*)(ws + 96 * MB);   // g f16 [M,512]
    f16*   XF  = (f16*)(ws + 112 * MB);  // x f16 [M,128] (4 MB)
    float* S1  = (float*)(ws + 116 * MB);
    float* G   = (float*)(ws + 118 * MB);
    float* cst = (float*)(ws + 120 * MB);
    float* BG  = (float*)(ws + 120 * MB + 64 * 1024);
    float* bc1 = (float*)(ws + 120 * MB + 128 * 1024);
    float* bc2 = (float*)(ws + 120 * MB + 192 * 1024);
    f16*   WB  = (f16*)(ws + 121 * MB);  // [1024][512] = [B_re; B_im]
    f16*   WC  = (f16*)(ws + 122 * MB);  // [512][1024] = [C_re | C_im]
    f16*   WG  = (f16*)(ws + 123 * MB);  // [1024][512] = [w1; w2]
    f16*   Wc1 = (f16*)(ws + 124 * MB);  // [512][128]
    f16*   Wc2 = (f16*)(ws + 124 * MB + 256 * 1024);  // [128][512]

    CvtJobs jobs;
    jobs.j[0] = {x,      XF,            Mrows * Hin, 7, Hin,  0};
    jobs.j[1] = {B_re,   WB,            Dm * Dm,     9, Dm,   0};
    jobs.j[2] = {B_im,   WB + 512 * Dm, Dm * Dm,     9, Dm,   0};
    jobs.j[3] = {C_re,   WC,            Dm * Dm,     9, 1024, 0};
    jobs.j[4] = {C_im,   WC,            Dm * Dm,     9, 1024, 512};
    jobs.j[5] = {glu_w1, WG,            Dm * Dm,     9, Dm,   0};
    jobs.j[6] = {glu_w2, WG + 512 * Dm, Dm * Dm,     9, Dm,   0};

    convert_k<<<dim3((Mrows * Hin) / 1024, 7), 256, 0, stream>>>(jobs);
    fuse_wc1<<<Dm, Hin, 0, stream>>>(W_enc, W_in, b_in, b_enc, Wc1, bc1);
    fuse_wc2<<<Hin, Dm, 0, stream>>>(W_out, W_dec, b_dec, b_out, Wc2, bc2);
    consts_k<<<1, Dm, 0, stream>>>(A_diag, log_steps, glu_b1, glu_b2, cst, BG);

    dim3 blk(256);

    // skip = x @ Wc1^T + bc1   (K=128, N=512)
    gemm_mfma<0, 1><<<dim3(128, 4), blk, 0, stream>>>(
        XF, Wc1, bc1, nullptr, nullptr, nullptr, F2, Mrows, Dm, Hin);
    // hn = layernorm(skip)
    layernorm_f16<<<Mrows / 4, 256, 0, stream>>>(F2, ln_g, ln_b, F3);
    // BU = hn @ [B_re;B_im]^T   (K=512, N=1024)
    gemm_mfma<0, 1><<<dim3(128, 8), blk, 0, stream>>>(
        F3, WB, nullptr, nullptr, nullptr, nullptr, BU, Mrows, 1024, Dm);
    // LinOSS scan (fp32 state)
    scan_phase1<<<Bb * NC, 512, 0, stream>>>(BU, cst, S1);
    scan_phase2<<<(Bb * Dm) / 256, 256, 0, stream>>>(S1, cst, G);
    scan_phase3<<<Bb * NC, 512, 0, stream>>>(BU, cst, G, XS);
    // g = gelu(XS @ WC^T + D*hn)   (K=1024, N=512)
    gemm_mfma<1, 1><<<dim3(128, 4), blk, 0, stream>>>(
        XS, WC, nullptr, F3, Dv, nullptr, GF, Mrows, Dm, 1024);
    // P = g @ [w1;w2]^T + [b1;b2]   (K=512, N=1024)  (overwrites BU)
    gemm_mfma<0, 1><<<dim3(128, 8), blk, 0, stream>>>(
        GF, WG, BG, nullptr, nullptr, nullptr, Pp, Mrows, 1024, Dm);
    // out = (skip + P1*sigmoid(P2)) @ Wc2^T + bc2   (K=512, N=128, fp32 out)
    gemm_mfma<4, 0><<<dim3(128, 1), blk, 0, stream>>>(
        Pp, Wc2, bc2, nullptr, nullptr, F2, (float*)d_out, Mrows, Hin, Dm);
}

// Round 7
// 333.363 us; speedup vs baseline: 1.2023x; 1.2023x over previous
//
#include <hip/hip_runtime.h>
#include <cstddef>
#include <cstdint>
#include <math.h>

typedef _Float16 f16;
typedef f16 f16x8 __attribute__((ext_vector_type(8)));
typedef f16 f16x4 __attribute__((ext_vector_type(4)));
typedef float f32x4 __attribute__((ext_vector_type(4)));

// ---------------- problem constants ----------------
constexpr int Bb   = 8;
constexpr int Ll   = 2048;
constexpr int Hin  = 128;
constexpr int Dm   = 512;
constexpr int Mrows = Bb * Ll;          // 16384
constexpr int NC   = 32;                // scan chunks per sequence
constexpr int CL   = Ll / NC;           // 64 timesteps per chunk
constexpr int SZ1  = Bb * NC * Dm;      // 131072 per state component
constexpr int SD   = 1024;              // interleaved [re|im] row stride

constexpr int TILE_ELE = 128 * 64;      // 128x64 f16 tile = 16 KB

// ---------------- device math helpers ----------------
static __device__ __forceinline__ float sigmoid_f(float x) {
    return 1.f / (1.f + expf(-x));
}
static __device__ __forceinline__ float gelu_tanh_f(float x) {
    float x3 = x * x * x;
    float t  = tanhf(0.7978845608028654f * (x + 0.044715f * x3));
    return 0.5f * x * (1.f + t);
}

// async global->LDS, 16 bytes per lane (linear LDS dest: wave base + lane*16)
static __device__ __forceinline__ void gld16(const f16* g, f16* l) {
    __builtin_amdgcn_global_load_lds(
        (const __attribute__((address_space(1))) void*)g,
        (__attribute__((address_space(3))) void*)l, 16, 0, 0);
}

// ---------------- weight-product fusion precompute ----------------
__global__ __launch_bounds__(128) void fuse_wc1(
    const float* __restrict__ Wenc, const float* __restrict__ Win,
    const float* __restrict__ b_in, const float* __restrict__ b_enc,
    f16* __restrict__ Wc1, float* __restrict__ bc1)
{
    const int d2 = blockIdx.x;      // 0..511
    const int t  = threadIdx.x;     // 0..127
    float acc = 0.f;
    for (int d = 0; d < Dm; ++d)
        acc = fmaf(Wenc[d2 * Dm + d], Win[d * Hin + t], acc);
    Wc1[d2 * Hin + t] = (f16)acc;
    if (t == 0) {
        float s = 0.f;
        for (int d = 0; d < Dm; ++d) s = fmaf(Wenc[d2 * Dm + d], b_in[d], s);
        bc1[d2] = s + b_enc[d2];
    }
}

__global__ __launch_bounds__(512) void fuse_wc2(
    const float* __restrict__ Wout, const float* __restrict__ Wdec,
    const float* __restrict__ b_dec, const float* __restrict__ b_out,
    f16* __restrict__ Wc2, float* __restrict__ bc2)
{
    const int o = blockIdx.x;   // 0..127
    const int t = threadIdx.x;  // 0..511
    float acc = 0.f;
    for (int d = 0; d < Dm; ++d)
        acc = fmaf(Wout[o * Dm + d], Wdec[d * Dm + t], acc);
    Wc2[o * Dm + t] = (f16)acc;
    if (t == 0) {
        float s = 0.f;
        for (int d = 0; d < Dm; ++d) s = fmaf(Wout[o * Dm + d], b_dec[d], s);
        bc2[o] = s + b_out[o];
    }
}

// ---------------- fp32 -> f16 conversion (pitched) ----------------
struct CvtJob { const float* s; f16* d; int n; int lgL; int pitch; int off; };
struct CvtJobs { CvtJob j[7]; };

__global__ __launch_bounds__(256) void convert_k(CvtJobs jobs) {
    const CvtJob jb = jobs.j[blockIdx.y];
    const int i = (blockIdx.x * 256 + threadIdx.x) * 4;
    if (i >= jb.n) return;
    const float4 v = *(const float4*)(jb.s + i);
    const int row = i >> jb.lgL;
    const int c   = i & ((1 << jb.lgL) - 1);
    f16x4 o;
    o.x = (f16)v.x; o.y = (f16)v.y; o.z = (f16)v.z; o.w = (f16)v.w;
    *(f16x4*)(jb.d + (size_t)row * jb.pitch + jb.off + c) = o;
}

// ---------------- fused MFMA GEMM (128x128 tile, BK=64, counted-vmcnt 2ph) ---
// KM=0: C = A@W^T + bias
// KM=1: C = gelu( A@W^T + DV[col]*EX[row,col] )
// KM=4: A built on the fly: h2 = SK + P[:,0:512]*sigmoid(P[:,512:1024]); C = h2@W^T + bias
template <int KM, int OUTF16>
__global__ __launch_bounds__(256, 2) void gemm_mfma(
    const f16* __restrict__ A, const f16* __restrict__ W,
    const float* __restrict__ bias,
    const f16* __restrict__ EX, const float* __restrict__ DV,
    const f16* __restrict__ SK,
    void* __restrict__ Cout, int M, int N, int K)
{
    __shared__ f16 smem[4 * TILE_ELE];  // A0,A1,B0,B1 (64 KB)

    const int tid = threadIdx.x;
    const int l   = tid & 63;
    const int wid = tid >> 6;
    const int wr  = wid >> 1;
    const int wc  = wid & 1;
    const int lc  = l & 15;
    const int lr  = l >> 4;
    const int row0 = blockIdx.x * 128;
    const int col0 = blockIdx.y * 128;

    const int NT = K >> 6;
    const int swz  = (l & 7) << 4;
    const int off0 = ((lr * 16) ^ swz) >> 1;
    const int off1 = ((64 + lr * 16) ^ swz) >> 1;

    f32x4 acc[4][4];
#pragma unroll
    for (int i = 0; i < 4; ++i)
#pragma unroll
        for (int j = 0; j < 4; ++j) acc[i][j] = (f32x4){0.f, 0.f, 0.f, 0.f};

    // stage one 128x64 tile: 4 x gld16 per thread; linear LDS dest,
    // inverse-swizzled global source (T2 both-sides involution)
#define STAGE(DST, SRC, RS)                                                  \
    {                                                                        \
        _Pragma("unroll")                                                    \
        for (int c = 0; c < 4; ++c) {                                        \
            const int chunk = c * 256 + tid;                                 \
            const int row   = chunk >> 3;                                    \
            const int kb    = ((chunk & 7) << 4) ^ ((row & 7) << 4);         \
            gld16(SRC + (size_t)row * RS + (kb >> 1), DST + chunk * 8);      \
        }                                                                    \
    }

#define COMPUTE(ASRC, BSRC)                                                  \
    {                                                                        \
        _Pragma("unroll")                                                    \
        for (int ks = 0; ks < 2; ++ks) {                                     \
            const int off = ks ? off1 : off0;                                \
            f16x8 aF[4], bF[4];                                              \
            _Pragma("unroll")                                                \
            for (int mi = 0; mi < 4; ++mi)                                   \
                aF[mi] = *(const f16x8*)((ASRC) + (wr * 64 + mi * 16 + lc) * 64 + off); \
            _Pragma("unroll")                                                \
            for (int ni = 0; ni < 4; ++ni)                                   \
                bF[ni] = *(const f16x8*)((BSRC) + (wc * 64 + ni * 16 + lc) * 64 + off); \
            _Pragma("unroll")                                                \
            for (int mi = 0; mi < 4; ++mi)                                   \
                _Pragma("unroll")                                            \
                for (int ni = 0; ni < 4; ++ni)                               \
                    acc[mi][ni] = __builtin_amdgcn_mfma_f32_16x16x32_f16(    \
                        aF[mi], bF[ni], acc[mi][ni], 0, 0, 0);               \
        }                                                                    \
    }

    if (KM != 4) {
        // ---- counted-vmcnt double-buffered pipeline (T3+T4 minimum) ----
        STAGE(smem, A + (size_t)row0 * K, K);
        STAGE(smem + 2 * TILE_ELE, W + (size_t)col0 * K, K);
        int cur = 0;
        for (int kt = 0; kt < NT; ++kt) {
            if (kt + 1 < NT) {
                const int k1 = (kt + 1) << 6;
                STAGE(smem + (cur ^ 1) * TILE_ELE, A + (size_t)row0 * K + k1, K);
                STAGE(smem + (2 + (cur ^ 1)) * TILE_ELE, W + (size_t)col0 * K + k1, K);
                asm volatile("s_waitcnt vmcnt(8)" ::: "memory");  // current tile landed; prefetch in flight
            } else {
                asm volatile("s_waitcnt vmcnt(0)" ::: "memory");
            }
            __builtin_amdgcn_s_barrier();
            COMPUTE(smem + cur * TILE_ELE, smem + (2 + cur) * TILE_ELE);
            __builtin_amdgcn_s_barrier();   // all reads of buf[cur] done before next overwrite
            cur ^= 1;
        }
    } else {
        // ---- KM=4: A computed on the fly (GLU combine), simple 2-barrier loop ----
        f16* As = smem;
        f16* Bs = smem + 2 * TILE_ELE;
        for (int kt = 0; kt < NT; ++kt) {
            const int k0 = kt << 6;
            __syncthreads();
#pragma unroll
            for (int c = 0; c < 4; ++c) {
                const int chunk = c * 256 + tid;
                const int row   = chunk >> 3;
                const int ke    = ((((chunk & 7) << 4) ^ ((row & 7) << 4)) >> 1);
                const size_t pb = (size_t)(row0 + row) * SD + k0 + ke;
                const f16x8 p1 = *(const f16x8*)(A + pb);
                const f16x8 p2 = *(const f16x8*)(A + pb + 512);
                const f16x8 sv = *(const f16x8*)(SK + (size_t)(row0 + row) * 512 + k0 + ke);
                f16x8 h;
#pragma unroll
                for (int j = 0; j < 8; ++j)
                    h[j] = (f16)((float)sv[j] + (float)p1[j] * sigmoid_f((float)p2[j]));
                *(f16x8*)(As + chunk * 8) = h;
            }
            STAGE(Bs, W + (size_t)col0 * K + k0, K);
            __syncthreads();
            COMPUTE(As, Bs);
        }
    }
#undef STAGE
#undef COMPUTE

    // ---------------- epilogue ----------------
    float* Cf32 = (float*)Cout;
    f16*   Cf16 = (f16*)Cout;
#pragma unroll
    for (int mi = 0; mi < 4; ++mi) {
#pragma unroll
        for (int ni = 0; ni < 4; ++ni) {
            const int col   = col0 + wc * 64 + ni * 16 + lc;
            const int rbase = row0 + wr * 64 + mi * 16 + lr * 4;
            const f32x4 v = acc[mi][ni];
            if (KM == 1) {
                const float dv = DV[col];
#pragma unroll
                for (int r = 0; r < 4; ++r) {
                    const size_t idx = (size_t)(rbase + r) * N + col;
                    const float o = gelu_tanh_f(v[r] + dv * (float)EX[idx]);
                    if (OUTF16) Cf16[idx] = (f16)o; else Cf32[idx] = o;
                }
            } else {
                const float bv = bias ? bias[col] : 0.f;
#pragma unroll
                for (int r = 0; r < 4; ++r) {
                    const float o = v[r] + bv;
                    const size_t idx = (size_t)(rbase + r) * N + col;
                    if (OUTF16) Cf16[idx] = (f16)o; else Cf32[idx] = o;
                }
            }
        }
    }
}

// ---------------- LayerNorm (rows of 512, f16 in/out) ----------------
__global__ __launch_bounds__(256) void layernorm_f16(
    const f16* __restrict__ X, const float* __restrict__ g,
    const float* __restrict__ b, f16* __restrict__ Y)
{
    const int lane = threadIdx.x & 63;
    const int w    = threadIdx.x >> 6;
    const int row  = blockIdx.x * 4 + w;
    const size_t base = (size_t)row * Dm + lane * 8;

    const f16x8 v = *(const f16x8*)(X + base);
    float x[8];
    float s = 0.f, q = 0.f;
#pragma unroll
    for (int i = 0; i < 8; ++i) {
        x[i] = (float)v[i];
        s += x[i]; q += x[i] * x[i];
    }
#pragma unroll
    for (int off = 32; off > 0; off >>= 1) {
        s += __shfl_xor(s, off);
        q += __shfl_xor(q, off);
    }
    const float mu  = s * (1.f / 512.f);
    const float var = q * (1.f / 512.f) - mu * mu;
    const float rs  = rsqrtf(var + 1e-5f);

    const float4 g0 = *(const float4*)(g + lane * 8);
    const float4 g1 = *(const float4*)(g + lane * 8 + 4);
    const float4 b0 = *(const float4*)(b + lane * 8);
    const float4 b1 = *(const float4*)(b + lane * 8 + 4);
    const float gg[8] = {g0.x, g0.y, g0.z, g0.w, g1.x, g1.y, g1.z, g1.w};
    const float bb[8] = {b0.x, b0.y, b0.z, b0.w, b1.x, b1.y, b1.z, b1.w};
    f16x8 o;
#pragma unroll
    for (int i = 0; i < 8; ++i)
        o[i] = (f16)((x[i] - mu) * rs * gg[i] + bb[i]);
    *(f16x8*)(Y + base) = o;
}

// ---------------- scan constants + concat GLU bias ----------------
__global__ void consts_k(const float* __restrict__ A_diag,
                         const float* __restrict__ log_steps,
                         const float* __restrict__ glu_b1,
                         const float* __restrict__ glu_b2,
                         float* __restrict__ cst, float* __restrict__ BG)
{
    const int n = threadIdx.x;
    const float a   = fmaxf(A_diag[n], 0.f);
    const float dt  = 1.f / (1.f + expf(-log_steps[n]));
    const float d2a = dt * dt * a;
    const float S   = 1.f / (1.f + d2a);
    const float m11 = 1.f - d2a * S;
    const float m12 = -dt * a * S;
    const float m21 = dt * S;
    const float m22 = S;
    cst[n]            = m11;
    cst[Dm + n]       = m12;
    cst[2 * Dm + n]   = m21;
    cst[3 * Dm + n]   = m22;
    cst[4 * Dm + n]   = m11 * dt;
    cst[5 * Dm + n]   = m21 * dt;
    BG[n]       = glu_b1[n];
    BG[Dm + n]  = glu_b2[n];
}

// ---------------- scan phase 1 (interleaved [re|im] rows of SD) --------------
__global__ __launch_bounds__(512) void scan_phase1(
    const f16* __restrict__ BU, const float* __restrict__ cst,
    float* __restrict__ S1)
{
    const int n = threadIdx.x;
    const int c = blockIdx.x & (NC - 1);
    const int b = blockIdx.x >> 5;
    const float m11 = cst[n],          m12 = cst[Dm + n];
    const float m21 = cst[2 * Dm + n], m22 = cst[3 * Dm + n];
    const float c1  = cst[4 * Dm + n], c2  = cst[5 * Dm + n];

    float zr = 0.f, xr = 0.f, zi = 0.f, xi = 0.f;
    const size_t base = ((size_t)b * Ll + (size_t)c * CL) * SD + n;
#pragma unroll 4
    for (int t = 0; t < CL; ++t) {
        const float br = (float)BU[base + (size_t)t * SD];
        const float bi = (float)BU[base + (size_t)t * SD + 512];
        const float zrn = fmaf(m11, zr, fmaf(m12, xr, c1 * br));
        const float xrn = fmaf(m21, zr, fmaf(m22, xr, c2 * br));
        const float zin = fmaf(m11, zi, fmaf(m12, xi, c1 * bi));
        const float xin = fmaf(m21, zi, fmaf(m22, xi, c2 * bi));
        zr = zrn; xr = xrn; zi = zin; xi = xin;
    }
    const int idx = blockIdx.x * Dm + n;
    S1[idx]            = zr;
    S1[SZ1 + idx]      = xr;
    S1[2 * SZ1 + idx]  = zi;
    S1[3 * SZ1 + idx]  = xi;
}

// ---------------- scan phase 2 ----------------
__global__ __launch_bounds__(256) void scan_phase2(
    const float* __restrict__ S1, const float* __restrict__ cst,
    float* __restrict__ G)
{
    const int gidx = blockIdx.x * 256 + threadIdx.x; // 0..4095
    const int n = gidx & (Dm - 1);
    const int b = gidx >> 9;
    const float m11 = cst[n],          m12 = cst[Dm + n];
    const float m21 = cst[2 * Dm + n], m22 = cst[3 * Dm + n];

    float p11 = 1.f, p12 = 0.f, p21 = 0.f, p22 = 1.f;
    for (int i = 0; i < CL; ++i) {
        const float q11 = m11 * p11 + m12 * p21;
        const float q12 = m11 * p12 + m12 * p22;
        const float q21 = m21 * p11 + m22 * p21;
        const float q22 = m21 * p12 + m22 * p22;
        p11 = q11; p12 = q12; p21 = q21; p22 = q22;
    }

    float gzr = 0.f, gxr = 0.f, gzi = 0.f, gxi = 0.f;
    for (int c = 0; c < NC; ++c) {
        const int idx = (b * NC + c) * Dm + n;
        G[idx]           = gzr;
        G[SZ1 + idx]     = gxr;
        G[2 * SZ1 + idx] = gzi;
        G[3 * SZ1 + idx] = gxi;
        const float szr = S1[idx],           sxr = S1[SZ1 + idx];
        const float szi = S1[2 * SZ1 + idx], sxi = S1[3 * SZ1 + idx];
        const float t1 = p11 * gzr + p12 * gxr + szr;
        const float t2 = p21 * gzr + p22 * gxr + sxr;
        const float t3 = p11 * gzi + p12 * gxi + szi;
        const float t4 = p21 * gzi + p22 * gxi + sxi;
        gzr = t1; gxr = t2; gzi = t3; gxi = t4;
    }
}

// ---------------- scan phase 3: re-scan; XS = [xr | -xi] interleaved ---------
__global__ __launch_bounds__(512) void scan_phase3(
    const f16* __restrict__ BU, const float* __restrict__ cst,
    const float* __restrict__ G, f16* __restrict__ XS)
{
    const int n = threadIdx.x;
    const int c = blockIdx.x & (NC - 1);
    const int b = blockIdx.x >> 5;
    const float m11 = cst[n],          m12 = cst[Dm + n];
    const float m21 = cst[2 * Dm + n], m22 = cst[3 * Dm + n];
    const float c1  = cst[4 * Dm + n], c2  = cst[5 * Dm + n];

    const int sidx = blockIdx.x * Dm + n;
    float zr = G[sidx];
    float xr = G[SZ1 + sidx];
    float zi = G[2 * SZ1 + sidx];
    float xi = G[3 * SZ1 + sidx];

    const size_t base = ((size_t)b * Ll + (size_t)c * CL) * SD + n;
#pragma unroll 4
    for (int t = 0; t < CL; ++t) {
        const float br = (float)BU[base + (size_t)t * SD];
        const float bi = (float)BU[base + (size_t)t * SD + 512];
        const float zrn = fmaf(m11, zr, fmaf(m12, xr, c1 * br));
        const float xrn = fmaf(m21, zr, fmaf(m22, xr, c2 * br));
        const float zin = fmaf(m11, zi, fmaf(m12, xi, c1 * bi));
        const float xin = fmaf(m21, zi, fmaf(m22, xi, c2 * bi));
        zr = zrn; xr = xrn; zi = zin; xi = xin;
        XS[base + (size_t)t * SD]       = (f16)xr;
        XS[base + (size_t)t * SD + 512] = (f16)(-xi);
    }
}

// ---------------- launch ----------------
extern "C" void kernel_launch(void* const* d_in, const int* in_sizes, int n_in,
                              void* d_out, int out_size, void* d_ws, size_t ws_size,
                              hipStream_t stream)
{
    const float* x         = (const float*)d_in[0];
    const float* W_in      = (const float*)d_in[1];
    const float* b_in      = (const float*)d_in[2];
    const float* W_enc     = (const float*)d_in[3];
    const float* b_enc     = (const float*)d_in[4];
    const float* ln_g      = (const float*)d_in[5];
    const float* ln_b      = (const float*)d_in[6];
    const float* A_diag    = (const float*)d_in[7];
    const float* log_steps = (const float*)d_in[8];
    const float* B_re      = (const float*)d_in[9];
    const float* B_im      = (const float*)d_in[10];
    const float* C_re      = (const float*)d_in[11];
    const float* C_im      = (const float*)d_in[12];
    const float* Dv        = (const float*)d_in[13];
    const float* glu_w1    = (const float*)d_in[14];
    const float* glu_b1    = (const float*)d_in[15];
    const float* glu_w2    = (const float*)d_in[16];
    const float* glu_b2    = (const float*)d_in[17];
    const float* W_dec     = (const float*)d_in[18];
    const float* b_dec     = (const float*)d_in[19];
    const float* W_out     = (const float*)d_in[20];
    const float* b_out     = (const float*)d_in[21];

    char* ws = (char*)d_ws;
    const size_t MB = 1 << 20;
    f16*   F2  = (f16*)(ws);             // skip f16 [M,512]
    f16*   F3  = (f16*)(ws + 16 * MB);   // hn f16 [M,512]
    f16*   XS  = (f16*)(ws + 32 * MB);   // [M,1024] = [xr | -xi]
    f16*   BU  = (f16*)(ws + 64 * MB);   // [M,1024] = [BuR | BuI]; later P
    f16*   Pp  = BU;                     // P aliases BU (dead after phase3)
    f16*   GF  = (f16*)(ws + 96 * MB);   // g f16 [M,512]
    f16*   XF  = (f16*)(ws + 112 * MB);  // x f16 [M,128] (4 MB)
    float* S1  = (float*)(ws + 116 * MB);
    float* G   = (float*)(ws + 118 * MB);
    float* cst = (float*)(ws + 120 * MB);
    float* BG  = (float*)(ws + 120 * MB + 64 * 1024);
    float* bc1 = (float*)(ws + 120 * MB + 128 * 1024);
    float* bc2 = (float*)(ws + 120 * MB + 192 * 1024);
    f16*   WB  = (f16*)(ws + 121 * MB);  // [1024][512] = [B_re; B_im]
    f16*   WC  = (f16*)(ws + 122 * MB);  // [512][1024] = [C_re | C_im]
    f16*   WG  = (f16*)(ws + 123 * MB);  // [1024][512] = [w1; w2]
    f16*   Wc1 = (f16*)(ws + 124 * MB);  // [512][128]
    f16*   Wc2 = (f16*)(ws + 124 * MB + 256 * 1024);  // [128][512]

    CvtJobs jobs;
    jobs.j[0] = {x,      XF,            Mrows * Hin, 7, Hin,  0};
    jobs.j[1] = {B_re,   WB,            Dm * Dm,     9, Dm,   0};
    jobs.j[2] = {B_im,   WB + 512 * Dm, Dm * Dm,     9, Dm,   0};
    jobs.j[3] = {C_re,   WC,            Dm * Dm,     9, 1024, 0};
    jobs.j[4] = {C_im,   WC,            Dm * Dm,     9, 1024, 512};
    jobs.j[5] = {glu_w1, WG,            Dm * Dm,     9, Dm,   0};
    jobs.j[6] = {glu_w2, WG + 512 * Dm, Dm * Dm,     9, Dm,   0};

    convert_k<<<dim3((Mrows * Hin) / 1024, 7), 256, 0, stream>>>(jobs);
    fuse_wc1<<<Dm, Hin, 0, stream>>>(W_enc, W_in, b_in, b_enc, Wc1, bc1);
    fuse_wc2<<<Hin, Dm, 0, stream>>>(W_out, W_dec, b_dec, b_out, Wc2, bc2);
    consts_k<<<1, Dm, 0, stream>>>(A_diag, log_steps, glu_b1, glu_b2, cst, BG);

    dim3 blk(256);

    // skip = x @ Wc1^T + bc1   (K=128, N=512)
    gemm_mfma<0, 1><<<dim3(128, 4), blk, 0, stream>>>(
        XF, Wc1, bc1, nullptr, nullptr, nullptr, F2, Mrows, Dm, Hin);
    // hn = layernorm(skip)
    layernorm_f16<<<Mrows / 4, 256, 0, stream>>>(F2, ln_g, ln_b, F3);
    // BU = hn @ [B_re;B_im]^T   (K=512, N=1024)
    gemm_mfma<0, 1><<<dim3(128, 8), blk, 0, stream>>>(
        F3, WB, nullptr, nullptr, nullptr, nullptr, BU, Mrows, 1024, Dm);
    // LinOSS scan (fp32 state)
    scan_phase1<<<Bb * NC, 512, 0, stream>>>(BU, cst, S1);
    scan_phase2<<<(Bb * Dm) / 256, 256, 0, stream>>>(S1, cst, G);
    scan_phase3<<<Bb * NC, 512, 0, stream>>>(BU, cst, G, XS);
    // g = gelu(XS @ WC^T + D*hn)   (K=1024, N=512)
    gemm_mfma<1, 1><<<dim3(128, 4), blk, 0, stream>>>(
        XS, WC, nullptr, F3, Dv, nullptr, GF, Mrows, Dm, 1024);
    // P = g @ [w1;w2]^T + [b1;b2]   (K=512, N=1024)  (overwrites BU)
    gemm_mfma<0, 1><<<dim3(128, 8), blk, 0, stream>>>(
        GF, WG, BG, nullptr, nullptr, nullptr, Pp, Mrows, 1024, Dm);
    // out = (skip + P1*sigmoid(P2)) @ Wc2^T + bc2   (K=512, N=128, fp32 out)
    gemm_mfma<4, 0><<<dim3(128, 1), blk, 0, stream>>>(
        Pp, Wc2, bc2, nullptr, nullptr, F2, (float*)d_out, Mrows, Hin, Dm);
}

// Round 8
// 330.845 us; speedup vs baseline: 1.2114x; 1.0076x over previous
//
#include <hip/hip_runtime.h>
#include <cstddef>
#include <cstdint>
#include <math.h>

typedef _Float16 f16;
typedef f16 f16x8 __attribute__((ext_vector_type(8)));
typedef f16 f16x4 __attribute__((ext_vector_type(4)));
typedef float f32x4 __attribute__((ext_vector_type(4)));

// ---------------- problem constants ----------------
constexpr int Bb   = 8;
constexpr int Ll   = 2048;
constexpr int Hin  = 128;
constexpr int Dm   = 512;
constexpr int Mrows = Bb * Ll;          // 16384
constexpr int NC   = 32;                // scan chunks per sequence
constexpr int CL   = Ll / NC;           // 64 timesteps per chunk
constexpr int SZ1  = Bb * NC * Dm;      // 131072 per state component
constexpr int SD   = 1024;              // interleaved [re|im] row stride

// ---------------- device math helpers ----------------
static __device__ __forceinline__ float sigmoid_f(float x) {
    return 1.f / (1.f + expf(-x));
}
static __device__ __forceinline__ float gelu_tanh_f(float x) {
    float x3 = x * x * x;
    float t  = tanhf(0.7978845608028654f * (x + 0.044715f * x3));
    return 0.5f * x * (1.f + t);
}

// async global->LDS, 16 bytes per lane (linear LDS dest: wave base + lane*16)
static __device__ __forceinline__ void gld16(const f16* g, f16* l) {
    __builtin_amdgcn_global_load_lds(
        (const __attribute__((address_space(1))) void*)g,
        (__attribute__((address_space(3))) void*)l, 16, 0, 0);
}

// ---------------- weight-product fusion precompute ----------------
__global__ __launch_bounds__(128) void fuse_wc1(
    const float* __restrict__ Wenc, const float* __restrict__ Win,
    const float* __restrict__ b_in, const float* __restrict__ b_enc,
    f16* __restrict__ Wc1, float* __restrict__ bc1)
{
    const int d2 = blockIdx.x;      // 0..511
    const int t  = threadIdx.x;     // 0..127
    float acc = 0.f;
    for (int d = 0; d < Dm; ++d)
        acc = fmaf(Wenc[d2 * Dm + d], Win[d * Hin + t], acc);
    Wc1[d2 * Hin + t] = (f16)acc;
    if (t == 0) {
        float s = 0.f;
        for (int d = 0; d < Dm; ++d) s = fmaf(Wenc[d2 * Dm + d], b_in[d], s);
        bc1[d2] = s + b_enc[d2];
    }
}

__global__ __launch_bounds__(512) void fuse_wc2(
    const float* __restrict__ Wout, const float* __restrict__ Wdec,
    const float* __restrict__ b_dec, const float* __restrict__ b_out,
    f16* __restrict__ Wc2, float* __restrict__ bc2)
{
    const int o = blockIdx.x;   // 0..127
    const int t = threadIdx.x;  // 0..511
    float acc = 0.f;
    for (int d = 0; d < Dm; ++d)
        acc = fmaf(Wout[o * Dm + d], Wdec[d * Dm + t], acc);
    Wc2[o * Dm + t] = (f16)acc;
    if (t == 0) {
        float s = 0.f;
        for (int d = 0; d < Dm; ++d) s = fmaf(Wout[o * Dm + d], b_dec[d], s);
        bc2[o] = s + b_out[o];
    }
}

// ---------------- fp32 -> f16 conversion (pitched) ----------------
struct CvtJob { const float* s; f16* d; int n; int lgL; int pitch; int off; };
struct CvtJobs { CvtJob j[7]; };

__global__ __launch_bounds__(256) void convert_k(CvtJobs jobs) {
    const CvtJob jb = jobs.j[blockIdx.y];
    const int i = (blockIdx.x * 256 + threadIdx.x) * 4;
    if (i >= jb.n) return;
    const float4 v = *(const float4*)(jb.s + i);
    const int row = i >> jb.lgL;
    const int c   = i & ((1 << jb.lgL) - 1);
    f16x4 o;
    o.x = (f16)v.x; o.y = (f16)v.y; o.z = (f16)v.z; o.w = (f16)v.w;
    *(f16x4*)(jb.d + (size_t)row * jb.pitch + jb.off + c) = o;
}

// ---------------- fused MFMA GEMM (BMx128 tile, BK=64, counted-vmcnt 2ph) ----
// KM=0: C = A@W^T + bias
// KM=1: C = gelu( A@W^T + DV[col]*EX[row,col] )
// KM=4: A built on the fly: h2 = SK + P[:,0:512]*sigmoid(P[:,512:1024]); C = h2@W^T + bias
template <int KM, int OUTF16, int BM>
__global__ __launch_bounds__(256, 2) void gemm_mfma(
    const f16* __restrict__ A, const f16* __restrict__ W,
    const float* __restrict__ bias,
    const f16* __restrict__ EX, const float* __restrict__ DV,
    const f16* __restrict__ SK,
    void* __restrict__ Cout, int M, int N, int K)
{
    constexpr int MR   = BM / 32;         // 16x16 frag rows per wave
    constexpr int AELE = BM * 64;         // A tile f16 count
    constexpr int BELE = 128 * 64;        // B tile f16 count
    constexpr int NBUF = (KM == 4) ? 1 : 2;
    __shared__ f16 smem[NBUF * (AELE + BELE)];

    const int tid = threadIdx.x;
    const int l   = tid & 63;
    const int wid = tid >> 6;
    const int wr  = wid >> 1;             // row half
    const int wc  = wid & 1;              // col half
    const int lc  = l & 15;
    const int lr  = l >> 4;
    const int row0 = blockIdx.x * BM;
    const int col0 = blockIdx.y * 128;

    const int NT = K >> 6;
    const int swz  = (l & 7) << 4;
    const int off0 = ((lr * 16) ^ swz) >> 1;
    const int off1 = ((64 + lr * 16) ^ swz) >> 1;

    f32x4 acc[MR][4];
#pragma unroll
    for (int i = 0; i < MR; ++i)
#pragma unroll
        for (int j = 0; j < 4; ++j) acc[i][j] = (f32x4){0.f, 0.f, 0.f, 0.f};

    // stage tiles: linear LDS dest, inverse-swizzled global source (T2 involution)
    auto stage_a = [&](f16* dst, const f16* src, int rs) {
#pragma unroll
        for (int c = 0; c < MR; ++c) {
            const int chunk = c * 256 + tid;
            const int row   = chunk >> 3;
            const int kb    = ((chunk & 7) << 4) ^ ((row & 7) << 4);
            gld16(src + (size_t)row * rs + (kb >> 1), dst + chunk * 8);
        }
    };
    auto stage_b = [&](f16* dst, const f16* src, int rs) {
#pragma unroll
        for (int c = 0; c < 4; ++c) {
            const int chunk = c * 256 + tid;
            const int row   = chunk >> 3;
            const int kb    = ((chunk & 7) << 4) ^ ((row & 7) << 4);
            gld16(src + (size_t)row * rs + (kb >> 1), dst + chunk * 8);
        }
    };
    auto compute = [&](const f16* As, const f16* Bs) {
#pragma unroll
        for (int ks = 0; ks < 2; ++ks) {
            const int off = ks ? off1 : off0;
            f16x8 aF[MR], bF[4];
#pragma unroll
            for (int mi = 0; mi < MR; ++mi)
                aF[mi] = *(const f16x8*)(As + (wr * (BM / 2) + mi * 16 + lc) * 64 + off);
#pragma unroll
            for (int ni = 0; ni < 4; ++ni)
                bF[ni] = *(const f16x8*)(Bs + (wc * 64 + ni * 16 + lc) * 64 + off);
#pragma unroll
            for (int mi = 0; mi < MR; ++mi)
#pragma unroll
                for (int ni = 0; ni < 4; ++ni)
                    acc[mi][ni] = __builtin_amdgcn_mfma_f32_16x16x32_f16(
                        aF[mi], bF[ni], acc[mi][ni], 0, 0, 0);
        }
    };

    if constexpr (KM != 4) {
        // ---- counted-vmcnt double-buffered pipeline ----
        stage_a(smem, A + (size_t)row0 * K, K);
        stage_b(smem + NBUF * AELE, W + (size_t)col0 * K, K);
        int cur = 0;
        for (int kt = 0; kt < NT; ++kt) {
            if (kt + 1 < NT) {
                const int k1 = (kt + 1) << 6;
                stage_a(smem + (cur ^ 1) * AELE, A + (size_t)row0 * K + k1, K);
                stage_b(smem + NBUF * AELE + (cur ^ 1) * BELE, W + (size_t)col0 * K + k1, K);
                if constexpr (MR == 4)      asm volatile("s_waitcnt vmcnt(8)" ::: "memory");
                else if constexpr (MR == 2) asm volatile("s_waitcnt vmcnt(6)" ::: "memory");
                else                        asm volatile("s_waitcnt vmcnt(5)" ::: "memory");
            } else {
                asm volatile("s_waitcnt vmcnt(0)" ::: "memory");
            }
            __builtin_amdgcn_s_barrier();
            compute(smem + cur * AELE, smem + NBUF * AELE + cur * BELE);
            __builtin_amdgcn_s_barrier();   // reads of buf[cur] done before overwrite
            cur ^= 1;
        }
    } else {
        // ---- KM=4: A computed on the fly (GLU combine), single-buffered ----
        f16* As = smem;
        f16* Bs = smem + AELE;
        for (int kt = 0; kt < NT; ++kt) {
            const int k0 = kt << 6;
            __syncthreads();
#pragma unroll
            for (int c = 0; c < MR; ++c) {
                const int chunk = c * 256 + tid;
                const int row   = chunk >> 3;
                const int ke    = ((((chunk & 7) << 4) ^ ((row & 7) << 4)) >> 1);
                const size_t pb = (size_t)(row0 + row) * SD + k0 + ke;
                const f16x8 p1 = *(const f16x8*)(A + pb);
                const f16x8 p2 = *(const f16x8*)(A + pb + 512);
                const f16x8 sv = *(const f16x8*)(SK + (size_t)(row0 + row) * 512 + k0 + ke);
                f16x8 h;
#pragma unroll
                for (int j = 0; j < 8; ++j)
                    h[j] = (f16)((float)sv[j] + (float)p1[j] * sigmoid_f((float)p2[j]));
                *(f16x8*)(As + chunk * 8) = h;
            }
            stage_b(Bs, W + (size_t)col0 * K + k0, K);
            __syncthreads();
            compute(As, Bs);
        }
    }

    // ---------------- epilogue ----------------
    float* Cf32 = (float*)Cout;
    f16*   Cf16 = (f16*)Cout;
#pragma unroll
    for (int mi = 0; mi < MR; ++mi) {
#pragma unroll
        for (int ni = 0; ni < 4; ++ni) {
            const int col   = col0 + wc * 64 + ni * 16 + lc;
            const int rbase = row0 + wr * (BM / 2) + mi * 16 + lr * 4;
            const f32x4 v = acc[mi][ni];
            if (KM == 1) {
                const float dv = DV[col];
#pragma unroll
                for (int r = 0; r < 4; ++r) {
                    const size_t idx = (size_t)(rbase + r) * N + col;
                    const float o = gelu_tanh_f(v[r] + dv * (float)EX[idx]);
                    if (OUTF16) Cf16[idx] = (f16)o; else Cf32[idx] = o;
                }
            } else {
                const float bv = bias ? bias[col] : 0.f;
#pragma unroll
                for (int r = 0; r < 4; ++r) {
                    const float o = v[r] + bv;
                    const size_t idx = (size_t)(rbase + r) * N + col;
                    if (OUTF16) Cf16[idx] = (f16)o; else Cf32[idx] = o;
                }
            }
        }
    }
}

// ---------------- LayerNorm (rows of 512, f16 in/out) ----------------
__global__ __launch_bounds__(256) void layernorm_f16(
    const f16* __restrict__ X, const float* __restrict__ g,
    const float* __restrict__ b, f16* __restrict__ Y)
{
    const int lane = threadIdx.x & 63;
    const int w    = threadIdx.x >> 6;
    const int row  = blockIdx.x * 4 + w;
    const size_t base = (size_t)row * Dm + lane * 8;

    const f16x8 v = *(const f16x8*)(X + base);
    float x[8];
    float s = 0.f, q = 0.f;
#pragma unroll
    for (int i = 0; i < 8; ++i) {
        x[i] = (float)v[i];
        s += x[i]; q += x[i] * x[i];
    }
#pragma unroll
    for (int off = 32; off > 0; off >>= 1) {
        s += __shfl_xor(s, off);
        q += __shfl_xor(q, off);
    }
    const float mu  = s * (1.f / 512.f);
    const float var = q * (1.f / 512.f) - mu * mu;
    const float rs  = rsqrtf(var + 1e-5f);

    const float4 g0 = *(const float4*)(g + lane * 8);
    const float4 g1 = *(const float4*)(g + lane * 8 + 4);
    const float4 b0 = *(const float4*)(b + lane * 8);
    const float4 b1 = *(const float4*)(b + lane * 8 + 4);
    const float gg[8] = {g0.x, g0.y, g0.z, g0.w, g1.x, g1.y, g1.z, g1.w};
    const float bb[8] = {b0.x, b0.y, b0.z, b0.w, b1.x, b1.y, b1.z, b1.w};
    f16x8 o;
#pragma unroll
    for (int i = 0; i < 8; ++i)
        o[i] = (f16)((x[i] - mu) * rs * gg[i] + bb[i]);
    *(f16x8*)(Y + base) = o;
}

// ---------------- scan constants + concat GLU bias ----------------
__global__ void consts_k(const float* __restrict__ A_diag,
                         const float* __restrict__ log_steps,
                         const float* __restrict__ glu_b1,
                         const float* __restrict__ glu_b2,
                         float* __restrict__ cst, float* __restrict__ BG)
{
    const int n = threadIdx.x;
    const float a   = fmaxf(A_diag[n], 0.f);
    const float dt  = 1.f / (1.f + expf(-log_steps[n]));
    const float d2a = dt * dt * a;
    const float S   = 1.f / (1.f + d2a);
    const float m11 = 1.f - d2a * S;
    const float m12 = -dt * a * S;
    const float m21 = dt * S;
    const float m22 = S;
    cst[n]            = m11;
    cst[Dm + n]       = m12;
    cst[2 * Dm + n]   = m21;
    cst[3 * Dm + n]   = m22;
    cst[4 * Dm + n]   = m11 * dt;
    cst[5 * Dm + n]   = m21 * dt;
    BG[n]       = glu_b1[n];
    BG[Dm + n]  = glu_b2[n];
}

// ---------------- scan phase 1 (interleaved [re|im] rows of SD) --------------
__global__ __launch_bounds__(512) void scan_phase1(
    const f16* __restrict__ BU, const float* __restrict__ cst,
    float* __restrict__ S1)
{
    const int n = threadIdx.x;
    const int c = blockIdx.x & (NC - 1);
    const int b = blockIdx.x >> 5;
    const float m11 = cst[n],          m12 = cst[Dm + n];
    const float m21 = cst[2 * Dm + n], m22 = cst[3 * Dm + n];
    const float c1  = cst[4 * Dm + n], c2  = cst[5 * Dm + n];

    float zr = 0.f, xr = 0.f, zi = 0.f, xi = 0.f;
    const size_t base = ((size_t)b * Ll + (size_t)c * CL) * SD + n;
#pragma unroll 4
    for (int t = 0; t < CL; ++t) {
        const float br = (float)BU[base + (size_t)t * SD];
        const float bi = (float)BU[base + (size_t)t * SD + 512];
        const float zrn = fmaf(m11, zr, fmaf(m12, xr, c1 * br));
        const float xrn = fmaf(m21, zr, fmaf(m22, xr, c2 * br));
        const float zin = fmaf(m11, zi, fmaf(m12, xi, c1 * bi));
        const float xin = fmaf(m21, zi, fmaf(m22, xi, c2 * bi));
        zr = zrn; xr = xrn; zi = zin; xi = xin;
    }
    const int idx = blockIdx.x * Dm + n;
    S1[idx]            = zr;
    S1[SZ1 + idx]      = xr;
    S1[2 * SZ1 + idx]  = zi;
    S1[3 * SZ1 + idx]  = xi;
}

// ---------------- scan phase 2 ----------------
__global__ __launch_bounds__(256) void scan_phase2(
    const float* __restrict__ S1, const float* __restrict__ cst,
    float* __restrict__ G)
{
    const int gidx = blockIdx.x * 256 + threadIdx.x; // 0..4095
    const int n = gidx & (Dm - 1);
    const int b = gidx >> 9;
    const float m11 = cst[n],          m12 = cst[Dm + n];
    const float m21 = cst[2 * Dm + n], m22 = cst[3 * Dm + n];

    float p11 = 1.f, p12 = 0.f, p21 = 0.f, p22 = 1.f;
    for (int i = 0; i < CL; ++i) {
        const float q11 = m11 * p11 + m12 * p21;
        const float q12 = m11 * p12 + m12 * p22;
        const float q21 = m21 * p11 + m22 * p21;
        const float q22 = m21 * p12 + m22 * p22;
        p11 = q11; p12 = q12; p21 = q21; p22 = q22;
    }

    float gzr = 0.f, gxr = 0.f, gzi = 0.f, gxi = 0.f;
    for (int c = 0; c < NC; ++c) {
        const int idx = (b * NC + c) * Dm + n;
        G[idx]           = gzr;
        G[SZ1 + idx]     = gxr;
        G[2 * SZ1 + idx] = gzi;
        G[3 * SZ1 + idx] = gxi;
        const float szr = S1[idx],           sxr = S1[SZ1 + idx];
        const float szi = S1[2 * SZ1 + idx], sxi = S1[3 * SZ1 + idx];
        const float t1 = p11 * gzr + p12 * gxr + szr;
        const float t2 = p21 * gzr + p22 * gxr + sxr;
        const float t3 = p11 * gzi + p12 * gxi + szi;
        const float t4 = p21 * gzi + p22 * gxi + sxi;
        gzr = t1; gxr = t2; gzi = t3; gxi = t4;
    }
}

// ---------------- scan phase 3: re-scan; XS = [xr | -xi] interleaved ---------
__global__ __launch_bounds__(512) void scan_phase3(
    const f16* __restrict__ BU, const float* __restrict__ cst,
    const float* __restrict__ G, f16* __restrict__ XS)
{
    const int n = threadIdx.x;
    const int c = blockIdx.x & (NC - 1);
    const int b = blockIdx.x >> 5;
    const float m11 = cst[n],          m12 = cst[Dm + n];
    const float m21 = cst[2 * Dm + n], m22 = cst[3 * Dm + n];
    const float c1  = cst[4 * Dm + n], c2  = cst[5 * Dm + n];

    const int sidx = blockIdx.x * Dm + n;
    float zr = G[sidx];
    float xr = G[SZ1 + sidx];
    float zi = G[2 * SZ1 + sidx];
    float xi = G[3 * SZ1 + sidx];

    const size_t base = ((size_t)b * Ll + (size_t)c * CL) * SD + n;
#pragma unroll 4
    for (int t = 0; t < CL; ++t) {
        const float br = (float)BU[base + (size_t)t * SD];
        const float bi = (float)BU[base + (size_t)t * SD + 512];
        const float zrn = fmaf(m11, zr, fmaf(m12, xr, c1 * br));
        const float xrn = fmaf(m21, zr, fmaf(m22, xr, c2 * br));
        const float zin = fmaf(m11, zi, fmaf(m12, xi, c1 * bi));
        const float xin = fmaf(m21, zi, fmaf(m22, xi, c2 * bi));
        zr = zrn; xr = xrn; zi = zin; xi = xin;
        XS[base + (size_t)t * SD]       = (f16)xr;
        XS[base + (size_t)t * SD + 512] = (f16)(-xi);
    }
}

// ---------------- launch ----------------
extern "C" void kernel_launch(void* const* d_in, const int* in_sizes, int n_in,
                              void* d_out, int out_size, void* d_ws, size_t ws_size,
                              hipStream_t stream)
{
    const float* x         = (const float*)d_in[0];
    const float* W_in      = (const float*)d_in[1];
    const float* b_in      = (const float*)d_in[2];
    const float* W_enc     = (const float*)d_in[3];
    const float* b_enc     = (const float*)d_in[4];
    const float* ln_g      = (const float*)d_in[5];
    const float* ln_b      = (const float*)d_in[6];
    const float* A_diag    = (const float*)d_in[7];
    const float* log_steps = (const float*)d_in[8];
    const float* B_re      = (const float*)d_in[9];
    const float* B_im      = (const float*)d_in[10];
    const float* C_re      = (const float*)d_in[11];
    const float* C_im      = (const float*)d_in[12];
    const float* Dv        = (const float*)d_in[13];
    const float* glu_w1    = (const float*)d_in[14];
    const float* glu_b1    = (const float*)d_in[15];
    const float* glu_w2    = (const float*)d_in[16];
    const float* glu_b2    = (const float*)d_in[17];
    const float* W_dec     = (const float*)d_in[18];
    const float* b_dec     = (const float*)d_in[19];
    const float* W_out     = (const float*)d_in[20];
    const float* b_out     = (const float*)d_in[21];

    char* ws = (char*)d_ws;
    const size_t MB = 1 << 20;
    f16*   F2  = (f16*)(ws);             // skip f16 [M,512]
    f16*   F3  = (f16*)(ws + 16 * MB);   // hn f16 [M,512]
    f16*   XS  = (f16*)(ws + 32 * MB);   // [M,1024] = [xr | -xi]
    f16*   BU  = (f16*)(ws + 64 * MB);   // [M,1024] = [BuR | BuI]; later P
    f16*   Pp  = BU;                     // P aliases BU (dead after phase3)
    f16*   GF  = (f16*)(ws + 96 * MB);   // g f16 [M,512]
    f16*   XF  = (f16*)(ws + 112 * MB);  // x f16 [M,128] (4 MB)
    float* S1  = (float*)(ws + 116 * MB);
    float* G   = (float*)(ws + 118 * MB);
    float* cst = (float*)(ws + 120 * MB);
    float* BG  = (float*)(ws + 120 * MB + 64 * 1024);
    float* bc1 = (float*)(ws + 120 * MB + 128 * 1024);
    float* bc2 = (float*)(ws + 120 * MB + 192 * 1024);
    f16*   WB  = (f16*)(ws + 121 * MB);  // [1024][512] = [B_re; B_im]
    f16*   WC  = (f16*)(ws + 122 * MB);  // [512][1024] = [C_re | C_im]
    f16*   WG  = (f16*)(ws + 123 * MB);  // [1024][512] = [w1; w2]
    f16*   Wc1 = (f16*)(ws + 124 * MB);  // [512][128]
    f16*   Wc2 = (f16*)(ws + 124 * MB + 256 * 1024);  // [128][512]

    CvtJobs jobs;
    jobs.j[0] = {x,      XF,            Mrows * Hin, 7, Hin,  0};
    jobs.j[1] = {B_re,   WB,            Dm * Dm,     9, Dm,   0};
    jobs.j[2] = {B_im,   WB + 512 * Dm, Dm * Dm,     9, Dm,   0};
    jobs.j[3] = {C_re,   WC,            Dm * Dm,     9, 1024, 0};
    jobs.j[4] = {C_im,   WC,            Dm * Dm,     9, 1024, 512};
    jobs.j[5] = {glu_w1, WG,            Dm * Dm,     9, Dm,   0};
    jobs.j[6] = {glu_w2, WG + 512 * Dm, Dm * Dm,     9, Dm,   0};

    convert_k<<<dim3((Mrows * Hin) / 1024, 7), 256, 0, stream>>>(jobs);
    fuse_wc1<<<Dm, Hin, 0, stream>>>(W_enc, W_in, b_in, b_enc, Wc1, bc1);
    fuse_wc2<<<Hin, Dm, 0, stream>>>(W_out, W_dec, b_dec, b_out, Wc2, bc2);
    consts_k<<<1, Dm, 0, stream>>>(A_diag, log_steps, glu_b1, glu_b2, cst, BG);

    dim3 blk(256);

    // skip = x @ Wc1^T + bc1   (K=128, N=512)
    gemm_mfma<0, 1, 64><<<dim3(Mrows / 64, 4), blk, 0, stream>>>(
        XF, Wc1, bc1, nullptr, nullptr, nullptr, F2, Mrows, Dm, Hin);
    // hn = layernorm(skip)
    layernorm_f16<<<Mrows / 4, 256, 0, stream>>>(F2, ln_g, ln_b, F3);
    // BU = hn @ [B_re;B_im]^T   (K=512, N=1024)
    gemm_mfma<0, 1, 64><<<dim3(Mrows / 64, 8), blk, 0, stream>>>(
        F3, WB, nullptr, nullptr, nullptr, nullptr, BU, Mrows, 1024, Dm);
    // LinOSS scan (fp32 state)
    scan_phase1<<<Bb * NC, 512, 0, stream>>>(BU, cst, S1);
    scan_phase2<<<(Bb * Dm) / 256, 256, 0, stream>>>(S1, cst, G);
    scan_phase3<<<Bb * NC, 512, 0, stream>>>(BU, cst, G, XS);
    // g = gelu(XS @ WC^T + D*hn)   (K=1024, N=512)
    gemm_mfma<1, 1, 64><<<dim3(Mrows / 64, 4), blk, 0, stream>>>(
        XS, WC, nullptr, F3, Dv, nullptr, GF, Mrows, Dm, 1024);
    // P = g @ [w1;w2]^T + [b1;b2]   (K=512, N=1024)  (overwrites BU)
    gemm_mfma<0, 1, 64><<<dim3(Mrows / 64, 8), blk, 0, stream>>>(
        GF, WG, BG, nullptr, nullptr, nullptr, Pp, Mrows, 1024, Dm);
    // out = (skip + P1*sigmoid(P2)) @ Wc2^T + bc2   (K=512, N=128, fp32 out)
    gemm_mfma<4, 0, 32><<<dim3(Mrows / 32, 1), blk, 0, stream>>>(
        Pp, Wc2, bc2, nullptr, nullptr, F2, (float*)d_out, Mrows, Hin, Dm);
}

// Round 9
// 315.510 us; speedup vs baseline: 1.2703x; 1.0486x over previous
//
#include <hip/hip_runtime.h>
#include <cstddef>
#include <cstdint>
#include <math.h>

typedef _Float16 f16;
typedef f16 f16x8 __attribute__((ext_vector_type(8)));
typedef f16 f16x4 __attribute__((ext_vector_type(4)));
typedef float f32x4 __attribute__((ext_vector_type(4)));

// ---------------- problem constants ----------------
constexpr int Bb   = 8;
constexpr int Ll   = 2048;
constexpr int Hin  = 128;
constexpr int Dm   = 512;
constexpr int Mrows = Bb * Ll;          // 16384
constexpr int NC   = 32;                // scan chunks per sequence
constexpr int CL   = Ll / NC;           // 64 timesteps per chunk
constexpr int SZ1  = Bb * NC * Dm;      // 131072 per state component
constexpr int SD   = 1024;              // interleaved [re|im] row stride

// ---------------- device math helpers ----------------
static __device__ __forceinline__ float sigmoid_f(float x) {
    return 1.f / (1.f + expf(-x));
}
static __device__ __forceinline__ float gelu_tanh_f(float x) {
    float x3 = x * x * x;
    float t  = tanhf(0.7978845608028654f * (x + 0.044715f * x3));
    return 0.5f * x * (1.f + t);
}

// async global->LDS, 16 bytes per lane (linear LDS dest: wave base + lane*16)
static __device__ __forceinline__ void gld16(const f16* g, f16* l) {
    __builtin_amdgcn_global_load_lds(
        (const __attribute__((address_space(1))) void*)g,
        (__attribute__((address_space(3))) void*)l, 16, 0, 0);
}

// ---------------- unified prep kernel ----------------
// y<7: fp32->f16 convert jobs (optionally row-interleaved for GLU weights)
// y=7: Wc1 = Wenc@Win (512x128) + bc1 ; y=8: Wc2 = Wout@Wdec (128x512) + bc2
// y=9: scan constants + interleaved GLU bias
struct CvtJob { const float* s; f16* d; int n; int lgL; int pitch; int off; int ilv; };
struct CvtJobs { CvtJob j[7]; };

__global__ __launch_bounds__(256) void prep_k(
    CvtJobs jobs,
    const float* __restrict__ Wenc, const float* __restrict__ Win,
    const float* __restrict__ b_in, const float* __restrict__ b_enc,
    const float* __restrict__ Wout, const float* __restrict__ Wdec,
    const float* __restrict__ b_dec, const float* __restrict__ b_out,
    const float* __restrict__ A_diag, const float* __restrict__ log_steps,
    const float* __restrict__ gb1, const float* __restrict__ gb2,
    f16* __restrict__ Wc1, float* __restrict__ bc1,
    f16* __restrict__ Wc2, float* __restrict__ bc2,
    float* __restrict__ cst, float* __restrict__ BG)
{
    const int y = blockIdx.y;
    if (y < 7) {
        const CvtJob jb = jobs.j[y];
        const int mask = (1 << jb.lgL) - 1;
        for (int i = (blockIdx.x * 256 + threadIdx.x) * 4; i < jb.n; i += 512 * 256 * 4) {
            const float4 v = *(const float4*)(jb.s + i);
            const int row = i >> jb.lgL;
            const int c   = i & mask;
            f16* dp = jb.ilv
                ? jb.d + (size_t)(((row >> 6) << 7) + (row & 63) + jb.off) * jb.pitch + c
                : jb.d + (size_t)row * jb.pitch + jb.off + c;
            f16x4 o;
            o.x = (f16)v.x; o.y = (f16)v.y; o.z = (f16)v.z; o.w = (f16)v.w;
            *(f16x4*)dp = o;
        }
    } else if (y == 7) {
        if (blockIdx.x >= 256) return;
        const int d2 = blockIdx.x * 2 + (threadIdx.x >> 7);
        const int t  = threadIdx.x & 127;
        float acc = 0.f;
        for (int d = 0; d < Dm; ++d)
            acc = fmaf(Wenc[d2 * Dm + d], Win[d * Hin + t], acc);
        Wc1[d2 * Hin + t] = (f16)acc;
        if (t == 0) {
            float s = 0.f;
            for (int d = 0; d < Dm; ++d) s = fmaf(Wenc[d2 * Dm + d], b_in[d], s);
            bc1[d2] = s + b_enc[d2];
        }
    } else if (y == 8) {
        if (blockIdx.x >= 128) return;
        const int o = blockIdx.x;
        for (int t = threadIdx.x; t < Dm; t += 256) {
            float acc = 0.f;
            for (int d = 0; d < Dm; ++d)
                acc = fmaf(Wout[o * Dm + d], Wdec[d * Dm + t], acc);
            Wc2[o * Dm + t] = (f16)acc;
        }
        if (threadIdx.x == 0) {
            float s = 0.f;
            for (int d = 0; d < Dm; ++d) s = fmaf(Wout[o * Dm + d], b_dec[d], s);
            bc2[o] = s + b_out[o];
        }
    } else {
        const int n = blockIdx.x * 256 + threadIdx.x;
        if (blockIdx.x >= 2 || n >= Dm) return;
        const float a   = fmaxf(A_diag[n], 0.f);
        const float dt  = 1.f / (1.f + expf(-log_steps[n]));
        const float d2a = dt * dt * a;
        const float S   = 1.f / (1.f + d2a);
        const float m11 = 1.f - d2a * S;
        const float m12 = -dt * a * S;
        const float m21 = dt * S;
        const float m22 = S;
        cst[n]            = m11;
        cst[Dm + n]       = m12;
        cst[2 * Dm + n]   = m21;
        cst[3 * Dm + n]   = m22;
        cst[4 * Dm + n]   = m11 * dt;
        cst[5 * Dm + n]   = m21 * dt;
        const int j = n >> 6, loc = n & 63;
        BG[(j << 7) + loc]      = gb1[n];   // interleaved [b1|b2] per 64-col group
        BG[(j << 7) + 64 + loc] = gb2[n];
    }
}

// ---------------- fused MFMA GEMM (BMx128 tile, BK=64, counted-vmcnt 2ph) ----
// KM=0: C = A@W^T + bias
// KM=1: C = gelu( A@W^T + DV[col]*EX[row,col] )
// KM=5: W is col-interleaved [w1|w2] per 64-col group; epilogue computes
//       h2 = EX + (P1+b1)*sigmoid(P2+b2) via LDS exchange; writes [M,512] f16
template <int KM, int OUTF16, int BM>
__global__ __launch_bounds__(256, 2) void gemm_mfma(
    const f16* __restrict__ A, const f16* __restrict__ W,
    const float* __restrict__ bias,
    const f16* __restrict__ EX, const float* __restrict__ DV,
    void* __restrict__ Cout, int M, int N, int K)
{
    constexpr int MR   = BM / 32;         // 16x16 frag rows per wave
    constexpr int AELE = BM * 64;         // A tile f16 count
    constexpr int BELE = 128 * 64;        // B tile f16 count
    __shared__ f16 smem[2 * (AELE + BELE)];

    const int tid = threadIdx.x;
    const int l   = tid & 63;
    const int wid = tid >> 6;
    const int wr  = wid >> 1;             // row half
    const int wc  = wid & 1;              // col half
    const int lc  = l & 15;
    const int lr  = l >> 4;
    const int row0 = blockIdx.x * BM;
    const int col0 = blockIdx.y * 128;

    const int NT = K >> 6;
    const int swz  = (l & 7) << 4;
    const int off0 = ((lr * 16) ^ swz) >> 1;
    const int off1 = ((64 + lr * 16) ^ swz) >> 1;

    f32x4 acc[MR][4];
#pragma unroll
    for (int i = 0; i < MR; ++i)
#pragma unroll
        for (int j = 0; j < 4; ++j) acc[i][j] = (f32x4){0.f, 0.f, 0.f, 0.f};

    auto stage_a = [&](f16* dst, const f16* src, int rs) {
#pragma unroll
        for (int c = 0; c < MR; ++c) {
            const int chunk = c * 256 + tid;
            const int row   = chunk >> 3;
            const int kb    = ((chunk & 7) << 4) ^ ((row & 7) << 4);
            gld16(src + (size_t)row * rs + (kb >> 1), dst + chunk * 8);
        }
    };
    auto stage_b = [&](f16* dst, const f16* src, int rs) {
#pragma unroll
        for (int c = 0; c < 4; ++c) {
            const int chunk = c * 256 + tid;
            const int row   = chunk >> 3;
            const int kb    = ((chunk & 7) << 4) ^ ((row & 7) << 4);
            gld16(src + (size_t)row * rs + (kb >> 1), dst + chunk * 8);
        }
    };
    auto compute = [&](const f16* As, const f16* Bs) {
#pragma unroll
        for (int ks = 0; ks < 2; ++ks) {
            const int off = ks ? off1 : off0;
            f16x8 aF[MR], bF[4];
#pragma unroll
            for (int mi = 0; mi < MR; ++mi)
                aF[mi] = *(const f16x8*)(As + (wr * (BM / 2) + mi * 16 + lc) * 64 + off);
#pragma unroll
            for (int ni = 0; ni < 4; ++ni)
                bF[ni] = *(const f16x8*)(Bs + (wc * 64 + ni * 16 + lc) * 64 + off);
#pragma unroll
            for (int mi = 0; mi < MR; ++mi)
#pragma unroll
                for (int ni = 0; ni < 4; ++ni)
                    acc[mi][ni] = __builtin_amdgcn_mfma_f32_16x16x32_f16(
                        aF[mi], bF[ni], acc[mi][ni], 0, 0, 0);
        }
    };

    // ---- counted-vmcnt double-buffered pipeline ----
    stage_a(smem, A + (size_t)row0 * K, K);
    stage_b(smem + 2 * AELE, W + (size_t)col0 * K, K);
    int cur = 0;
    for (int kt = 0; kt < NT; ++kt) {
        if (kt + 1 < NT) {
            const int k1 = (kt + 1) << 6;
            stage_a(smem + (cur ^ 1) * AELE, A + (size_t)row0 * K + k1, K);
            stage_b(smem + 2 * AELE + (cur ^ 1) * BELE, W + (size_t)col0 * K + k1, K);
            if constexpr (MR == 2)      asm volatile("s_waitcnt vmcnt(6)" ::: "memory");
            else if constexpr (MR == 1) asm volatile("s_waitcnt vmcnt(5)" ::: "memory");
            else                        asm volatile("s_waitcnt vmcnt(8)" ::: "memory");
        } else {
            asm volatile("s_waitcnt vmcnt(0)" ::: "memory");
        }
        __builtin_amdgcn_s_barrier();
        compute(smem + cur * AELE, smem + 2 * AELE + cur * BELE);
        __builtin_amdgcn_s_barrier();   // reads of buf[cur] done before overwrite
        cur ^= 1;
    }

    // ---------------- epilogue ----------------
    float* Cf32 = (float*)Cout;
    f16*   Cf16 = (f16*)Cout;
    if constexpr (KM == 5) {
        // GLU combine: wc=1 waves hold P2 cols, wc=0 hold P1 cols (same 64 h-cols)
        float* sig = (float*)smem;  // [BM][65] padded
        __syncthreads();
        if (wc == 1) {
#pragma unroll
            for (int mi = 0; mi < MR; ++mi)
#pragma unroll
                for (int ni = 0; ni < 4; ++ni) {
                    const int col = col0 + 64 + ni * 16 + lc;
                    const int rl0 = wr * (BM / 2) + mi * 16 + lr * 4;
                    const f32x4 v = acc[mi][ni];
#pragma unroll
                    for (int r = 0; r < 4; ++r)
                        sig[(rl0 + r) * 65 + ni * 16 + lc] = sigmoid_f(v[r] + bias[col]);
                }
        }
        __syncthreads();
        if (wc == 0) {
#pragma unroll
            for (int mi = 0; mi < MR; ++mi)
#pragma unroll
                for (int ni = 0; ni < 4; ++ni) {
                    const int cl   = ni * 16 + lc;
                    const int col  = col0 + cl;              // bias index (interleaved)
                    const int hcol = blockIdx.y * 64 + cl;   // h2 column in [0,512)
                    const int rl0  = wr * (BM / 2) + mi * 16 + lr * 4;
                    const f32x4 v = acc[mi][ni];
#pragma unroll
                    for (int r = 0; r < 4; ++r) {
                        const int row = row0 + rl0 + r;
                        const float o = (float)EX[(size_t)row * Dm + hcol]
                                      + (v[r] + bias[col]) * sig[(rl0 + r) * 65 + cl];
                        Cf16[(size_t)row * Dm + hcol] = (f16)o;
                    }
                }
        }
        return;
    }
#pragma unroll
    for (int mi = 0; mi < MR; ++mi) {
#pragma unroll
        for (int ni = 0; ni < 4; ++ni) {
            const int col   = col0 + wc * 64 + ni * 16 + lc;
            const int rbase = row0 + wr * (BM / 2) + mi * 16 + lr * 4;
            const f32x4 v = acc[mi][ni];
            if (KM == 1) {
                const float dv = DV[col];
#pragma unroll
                for (int r = 0; r < 4; ++r) {
                    const size_t idx = (size_t)(rbase + r) * N + col;
                    const float o = gelu_tanh_f(v[r] + dv * (float)EX[idx]);
                    if (OUTF16) Cf16[idx] = (f16)o; else Cf32[idx] = o;
                }
            } else {
                const float bv = bias ? bias[col] : 0.f;
#pragma unroll
                for (int r = 0; r < 4; ++r) {
                    const float o = v[r] + bv;
                    const size_t idx = (size_t)(rbase + r) * N + col;
                    if (OUTF16) Cf16[idx] = (f16)o; else Cf32[idx] = o;
                }
            }
        }
    }
}

// ---------------- LayerNorm (rows of 512, f16 in/out) ----------------
__global__ __launch_bounds__(256) void layernorm_f16(
    const f16* __restrict__ X, const float* __restrict__ g,
    const float* __restrict__ b, f16* __restrict__ Y)
{
    const int lane = threadIdx.x & 63;
    const int w    = threadIdx.x >> 6;
    const int row  = blockIdx.x * 4 + w;
    const size_t base = (size_t)row * Dm + lane * 8;

    const f16x8 v = *(const f16x8*)(X + base);
    float x[8];
    float s = 0.f, q = 0.f;
#pragma unroll
    for (int i = 0; i < 8; ++i) {
        x[i] = (float)v[i];
        s += x[i]; q += x[i] * x[i];
    }
#pragma unroll
    for (int off = 32; off > 0; off >>= 1) {
        s += __shfl_xor(s, off);
        q += __shfl_xor(q, off);
    }
    const float mu  = s * (1.f / 512.f);
    const float var = q * (1.f / 512.f) - mu * mu;
    const float rs  = rsqrtf(var + 1e-5f);

    const float4 g0 = *(const float4*)(g + lane * 8);
    const float4 g1 = *(const float4*)(g + lane * 8 + 4);
    const float4 b0 = *(const float4*)(b + lane * 8);
    const float4 b1 = *(const float4*)(b + lane * 8 + 4);
    const float gg[8] = {g0.x, g0.y, g0.z, g0.w, g1.x, g1.y, g1.z, g1.w};
    const float bb[8] = {b0.x, b0.y, b0.z, b0.w, b1.x, b1.y, b1.z, b1.w};
    f16x8 o;
#pragma unroll
    for (int i = 0; i < 8; ++i)
        o[i] = (f16)((x[i] - mu) * rs * gg[i] + bb[i]);
    *(f16x8*)(Y + base) = o;
}

// ---------------- scan phase 1 (interleaved [re|im] rows of SD) --------------
__global__ __launch_bounds__(512) void scan_phase1(
    const f16* __restrict__ BU, const float* __restrict__ cst,
    float* __restrict__ S1)
{
    const int n = threadIdx.x;
    const int c = blockIdx.x & (NC - 1);
    const int b = blockIdx.x >> 5;
    const float m11 = cst[n],          m12 = cst[Dm + n];
    const float m21 = cst[2 * Dm + n], m22 = cst[3 * Dm + n];
    const float c1  = cst[4 * Dm + n], c2  = cst[5 * Dm + n];

    float zr = 0.f, xr = 0.f, zi = 0.f, xi = 0.f;
    const size_t base = ((size_t)b * Ll + (size_t)c * CL) * SD + n;
#pragma unroll 4
    for (int t = 0; t < CL; ++t) {
        const float br = (float)BU[base + (size_t)t * SD];
        const float bi = (float)BU[base + (size_t)t * SD + 512];
        const float zrn = fmaf(m11, zr, fmaf(m12, xr, c1 * br));
        const float xrn = fmaf(m21, zr, fmaf(m22, xr, c2 * br));
        const float zin = fmaf(m11, zi, fmaf(m12, xi, c1 * bi));
        const float xin = fmaf(m21, zi, fmaf(m22, xi, c2 * bi));
        zr = zrn; xr = xrn; zi = zin; xi = xin;
    }
    const int idx = blockIdx.x * Dm + n;
    S1[idx]            = zr;
    S1[SZ1 + idx]      = xr;
    S1[2 * SZ1 + idx]  = zi;
    S1[3 * SZ1 + idx]  = xi;
}

// ---------------- scan phase 2 ----------------
__global__ __launch_bounds__(256) void scan_phase2(
    const float* __restrict__ S1, const float* __restrict__ cst,
    float* __restrict__ G)
{
    const int gidx = blockIdx.x * 256 + threadIdx.x; // 0..4095
    const int n = gidx & (Dm - 1);
    const int b = gidx >> 9;
    const float m11 = cst[n],          m12 = cst[Dm + n];
    const float m21 = cst[2 * Dm + n], m22 = cst[3 * Dm + n];

    float p11 = 1.f, p12 = 0.f, p21 = 0.f, p22 = 1.f;
    for (int i = 0; i < CL; ++i) {
        const float q11 = m11 * p11 + m12 * p21;
        const float q12 = m11 * p12 + m12 * p22;
        const float q21 = m21 * p11 + m22 * p21;
        const float q22 = m21 * p12 + m22 * p22;
        p11 = q11; p12 = q12; p21 = q21; p22 = q22;
    }

    float gzr = 0.f, gxr = 0.f, gzi = 0.f, gxi = 0.f;
    for (int c = 0; c < NC; ++c) {
        const int idx = (b * NC + c) * Dm + n;
        G[idx]           = gzr;
        G[SZ1 + idx]     = gxr;
        G[2 * SZ1 + idx] = gzi;
        G[3 * SZ1 + idx] = gxi;
        const float szr = S1[idx],           sxr = S1[SZ1 + idx];
        const float szi = S1[2 * SZ1 + idx], sxi = S1[3 * SZ1 + idx];
        const float t1 = p11 * gzr + p12 * gxr + szr;
        const float t2 = p21 * gzr + p22 * gxr + sxr;
        const float t3 = p11 * gzi + p12 * gxi + szi;
        const float t4 = p21 * gzi + p22 * gxi + sxi;
        gzr = t1; gxr = t2; gzi = t3; gxi = t4;
    }
}

// ---------------- scan phase 3: re-scan; XS = [xr | -xi] interleaved ---------
__global__ __launch_bounds__(512) void scan_phase3(
    const f16* __restrict__ BU, const float* __restrict__ cst,
    const float* __restrict__ G, f16* __restrict__ XS)
{
    const int n = threadIdx.x;
    const int c = blockIdx.x & (NC - 1);
    const int b = blockIdx.x >> 5;
    const float m11 = cst[n],          m12 = cst[Dm + n];
    const float m21 = cst[2 * Dm + n], m22 = cst[3 * Dm + n];
    const float c1  = cst[4 * Dm + n], c2  = cst[5 * Dm + n];

    const int sidx = blockIdx.x * Dm + n;
    float zr = G[sidx];
    float xr = G[SZ1 + sidx];
    float zi = G[2 * SZ1 + sidx];
    float xi = G[3 * SZ1 + sidx];

    const size_t base = ((size_t)b * Ll + (size_t)c * CL) * SD + n;
#pragma unroll 4
    for (int t = 0; t < CL; ++t) {
        const float br = (float)BU[base + (size_t)t * SD];
        const float bi = (float)BU[base + (size_t)t * SD + 512];
        const float zrn = fmaf(m11, zr, fmaf(m12, xr, c1 * br));
        const float xrn = fmaf(m21, zr, fmaf(m22, xr, c2 * br));
        const float zin = fmaf(m11, zi, fmaf(m12, xi, c1 * bi));
        const float xin = fmaf(m21, zi, fmaf(m22, xi, c2 * bi));
        zr = zrn; xr = xrn; zi = zin; xi = xin;
        XS[base + (size_t)t * SD]       = (f16)xr;
        XS[base + (size_t)t * SD + 512] = (f16)(-xi);
    }
}

// ---------------- launch ----------------
extern "C" void kernel_launch(void* const* d_in, const int* in_sizes, int n_in,
                              void* d_out, int out_size, void* d_ws, size_t ws_size,
                              hipStream_t stream)
{
    const float* x         = (const float*)d_in[0];
    const float* W_in      = (const float*)d_in[1];
    const float* b_in      = (const float*)d_in[2];
    const float* W_enc     = (const float*)d_in[3];
    const float* b_enc     = (const float*)d_in[4];
    const float* ln_g      = (const float*)d_in[5];
    const float* ln_b      = (const float*)d_in[6];
    const float* A_diag    = (const float*)d_in[7];
    const float* log_steps = (const float*)d_in[8];
    const float* B_re      = (const float*)d_in[9];
    const float* B_im      = (const float*)d_in[10];
    const float* C_re      = (const float*)d_in[11];
    const float* C_im      = (const float*)d_in[12];
    const float* Dv        = (const float*)d_in[13];
    const float* glu_w1    = (const float*)d_in[14];
    const float* glu_b1    = (const float*)d_in[15];
    const float* glu_w2    = (const float*)d_in[16];
    const float* glu_b2    = (const float*)d_in[17];
    const float* W_dec     = (const float*)d_in[18];
    const float* b_dec     = (const float*)d_in[19];
    const float* W_out     = (const float*)d_in[20];
    const float* b_out     = (const float*)d_in[21];

    char* ws = (char*)d_ws;
    const size_t MB = 1 << 20;
    f16*   F2  = (f16*)(ws);             // skip f16 [M,512]
    f16*   F3  = (f16*)(ws + 16 * MB);   // hn f16 [M,512]; later h2
    f16*   XS  = (f16*)(ws + 32 * MB);   // [M,1024] = [xr | -xi]
    f16*   BU  = (f16*)(ws + 64 * MB);   // [M,1024] = [BuR | BuI]
    f16*   GF  = (f16*)(ws + 96 * MB);   // g f16 [M,512]
    f16*   XF  = (f16*)(ws + 112 * MB);  // x f16 [M,128] (4 MB)
    float* S1  = (float*)(ws + 116 * MB);
    float* G   = (float*)(ws + 118 * MB);
    float* cst = (float*)(ws + 120 * MB);
    float* BG  = (float*)(ws + 120 * MB + 64 * 1024);   // interleaved [b1|b2]
    float* bc1 = (float*)(ws + 120 * MB + 128 * 1024);
    float* bc2 = (float*)(ws + 120 * MB + 192 * 1024);
    f16*   WB  = (f16*)(ws + 121 * MB);  // [1024][512] = [B_re; B_im]
    f16*   WC  = (f16*)(ws + 122 * MB);  // [512][1024] = [C_re | C_im]
    f16*   WG  = (f16*)(ws + 123 * MB);  // [1024][512] = interleaved [w1|w2] per 64
    f16*   Wc1 = (f16*)(ws + 124 * MB);  // [512][128]
    f16*   Wc2 = (f16*)(ws + 124 * MB + 256 * 1024);  // [128][512]

    CvtJobs jobs;
    jobs.j[0] = {x,      XF,            Mrows * Hin, 7, Hin,  0,   0};
    jobs.j[1] = {B_re,   WB,            Dm * Dm,     9, Dm,   0,   0};
    jobs.j[2] = {B_im,   WB + 512 * Dm, Dm * Dm,     9, Dm,   0,   0};
    jobs.j[3] = {C_re,   WC,            Dm * Dm,     9, 1024, 0,   0};
    jobs.j[4] = {C_im,   WC,            Dm * Dm,     9, 1024, 512, 0};
    jobs.j[5] = {glu_w1, WG,            Dm * Dm,     9, Dm,   0,   1};
    jobs.j[6] = {glu_w2, WG,            Dm * Dm,     9, Dm,   64,  1};

    prep_k<<<dim3(512, 10), 256, 0, stream>>>(
        jobs, W_enc, W_in, b_in, b_enc, W_out, W_dec, b_dec, b_out,
        A_diag, log_steps, glu_b1, glu_b2, Wc1, bc1, Wc2, bc2, cst, BG);

    dim3 blk(256);

    // skip = x @ Wc1^T + bc1   (K=128, N=512)
    gemm_mfma<0, 1, 64><<<dim3(Mrows / 64, 4), blk, 0, stream>>>(
        XF, Wc1, bc1, nullptr, nullptr, F2, Mrows, Dm, Hin);
    // hn = layernorm(skip)
    layernorm_f16<<<Mrows / 4, 256, 0, stream>>>(F2, ln_g, ln_b, F3);
    // BU = hn @ [B_re;B_im]^T   (K=512, N=1024)
    gemm_mfma<0, 1, 64><<<dim3(Mrows / 64, 8), blk, 0, stream>>>(
        F3, WB, nullptr, nullptr, nullptr, BU, Mrows, 1024, Dm);
    // LinOSS scan (fp32 state)
    scan_phase1<<<Bb * NC, 512, 0, stream>>>(BU, cst, S1);
    scan_phase2<<<(Bb * Dm) / 256, 256, 0, stream>>>(S1, cst, G);
    scan_phase3<<<Bb * NC, 512, 0, stream>>>(BU, cst, G, XS);
    // g = gelu(XS @ WC^T + D*hn)   (K=1024, N=512)
    gemm_mfma<1, 1, 64><<<dim3(Mrows / 64, 4), blk, 0, stream>>>(
        XS, WC, nullptr, F3, Dv, GF, Mrows, Dm, 1024);
    // h2 = skip + (g@w1^T+b1)*sigmoid(g@w2^T+b2)  (K=512, interleaved N=1024 -> h2[M,512])
    gemm_mfma<5, 1, 64><<<dim3(Mrows / 64, 8), blk, 0, stream>>>(
        GF, WG, BG, F2, nullptr, F3, Mrows, 1024, Dm);
    // out = h2 @ Wc2^T + bc2   (K=512, N=128, fp32 out)
    gemm_mfma<0, 0, 32><<<dim3(Mrows / 32, 1), blk, 0, stream>>>(
        F3, Wc2, bc2, nullptr, nullptr, (float*)d_out, Mrows, Hin, Dm);
}

// Round 11
// 297.022 us; speedup vs baseline: 1.3494x; 1.0622x over previous
//
#include <hip/hip_runtime.h>
#include <cstddef>
#include <cstdint>
#include <math.h>

typedef _Float16 f16;
typedef f16 f16x8 __attribute__((ext_vector_type(8)));
typedef f16 f16x4 __attribute__((ext_vector_type(4)));
typedef float f32x4 __attribute__((ext_vector_type(4)));

// ---------------- problem constants ----------------
constexpr int Bb   = 8;
constexpr int Ll   = 2048;
constexpr int Hin  = 128;
constexpr int Dm   = 512;
constexpr int Mrows = Bb * Ll;          // 16384
constexpr int NC   = 32;                // scan chunks per sequence
constexpr int CL   = Ll / NC;           // 64 timesteps per chunk
constexpr int SZ1  = Bb * NC * Dm;      // 131072 per state component
constexpr int SD   = 1024;              // interleaved [re|im] row stride

// ---------------- device math helpers ----------------
static __device__ __forceinline__ float sigmoid_f(float x) {
    return 1.f / (1.f + expf(-x));
}
static __device__ __forceinline__ float gelu_tanh_f(float x) {
    float x3 = x * x * x;
    float t  = tanhf(0.7978845608028654f * (x + 0.044715f * x3));
    return 0.5f * x * (1.f + t);
}

// async global->LDS, 16 bytes per lane (linear LDS dest: wave base + lane*16)
static __device__ __forceinline__ void gld16(const f16* g, f16* l) {
    __builtin_amdgcn_global_load_lds(
        (const __attribute__((address_space(1))) void*)g,
        (__attribute__((address_space(3))) void*)l, 16, 0, 0);
}

// hard barrier: real compiler memory fence + HW barrier (prevents any
// reordering of gld16 / ds_read across it — rule #18 / m152 hardening)
static __device__ __forceinline__ void hard_barrier() {
    __builtin_amdgcn_sched_barrier(0);
    asm volatile("s_barrier" ::: "memory");
    __builtin_amdgcn_sched_barrier(0);
}

// ---------------- unified prep kernel ----------------
// y<7: fp32->f16 convert jobs (optionally row-interleaved for GLU weights)
// y=7: Wc1 = Wenc@Win (512x128) + bc1 ; y=8: Wc2 = Wout@Wdec (128x512) + bc2
// y=9: scan constants + interleaved GLU bias
struct CvtJob { const float* s; f16* d; int n; int lgL; int pitch; int off; int ilv; };
struct CvtJobs { CvtJob j[7]; };

__global__ __launch_bounds__(256) void prep_k(
    CvtJobs jobs,
    const float* __restrict__ Wenc, const float* __restrict__ Win,
    const float* __restrict__ b_in, const float* __restrict__ b_enc,
    const float* __restrict__ Wout, const float* __restrict__ Wdec,
    const float* __restrict__ b_dec, const float* __restrict__ b_out,
    const float* __restrict__ A_diag, const float* __restrict__ log_steps,
    const float* __restrict__ gb1, const float* __restrict__ gb2,
    f16* __restrict__ Wc1, float* __restrict__ bc1,
    f16* __restrict__ Wc2, float* __restrict__ bc2,
    float* __restrict__ cst, float* __restrict__ BG)
{
    const int y = blockIdx.y;
    if (y < 7) {
        const CvtJob jb = jobs.j[y];
        const int mask = (1 << jb.lgL) - 1;
        for (int i = (blockIdx.x * 256 + threadIdx.x) * 4; i < jb.n; i += 512 * 256 * 4) {
            const float4 v = *(const float4*)(jb.s + i);
            const int row = i >> jb.lgL;
            const int c   = i & mask;
            f16* dp = jb.ilv
                ? jb.d + (size_t)(((row >> 6) << 7) + (row & 63) + jb.off) * jb.pitch + c
                : jb.d + (size_t)row * jb.pitch + jb.off + c;
            f16x4 o;
            o.x = (f16)v.x; o.y = (f16)v.y; o.z = (f16)v.z; o.w = (f16)v.w;
            *(f16x4*)dp = o;
        }
    } else if (y == 7) {
        // Wc1 = Wenc @ Win: 8 independent chains -> loads pipeline
        if (blockIdx.x >= 256) return;
        const int d2 = blockIdx.x * 2 + (threadIdx.x >> 7);
        const int t  = threadIdx.x & 127;
        float a0 = 0.f, a1 = 0.f, a2 = 0.f, a3 = 0.f;
        float a4 = 0.f, a5 = 0.f, a6 = 0.f, a7 = 0.f;
        const float* wr = Wenc + (size_t)d2 * Dm;
        for (int d = 0; d < Dm; d += 8) {
            a0 = fmaf(wr[d + 0], Win[(d + 0) * Hin + t], a0);
            a1 = fmaf(wr[d + 1], Win[(d + 1) * Hin + t], a1);
            a2 = fmaf(wr[d + 2], Win[(d + 2) * Hin + t], a2);
            a3 = fmaf(wr[d + 3], Win[(d + 3) * Hin + t], a3);
            a4 = fmaf(wr[d + 4], Win[(d + 4) * Hin + t], a4);
            a5 = fmaf(wr[d + 5], Win[(d + 5) * Hin + t], a5);
            a6 = fmaf(wr[d + 6], Win[(d + 6) * Hin + t], a6);
            a7 = fmaf(wr[d + 7], Win[(d + 7) * Hin + t], a7);
        }
        Wc1[d2 * Hin + t] = (f16)(((a0 + a1) + (a2 + a3)) + ((a4 + a5) + (a6 + a7)));
        if (t < 64) {  // full wave per d2 group
            float p = 0.f;
#pragma unroll
            for (int j = 0; j < 8; ++j)
                p = fmaf(wr[t + 64 * j], b_in[t + 64 * j], p);
#pragma unroll
            for (int off = 32; off > 0; off >>= 1) p += __shfl_down(p, off);
            if (t == 0) bc1[d2] = p + b_enc[d2];
        }
    } else if (y == 8) {
        // Wc2 = Wout @ Wdec: float2 across t, 4-deep unroll across d (8 chains)
        if (blockIdx.x >= 128) return;
        const int o  = blockIdx.x;
        const int t0 = threadIdx.x * 2;
        const float* wo = Wout + (size_t)o * Dm;
        float x0 = 0.f, y0 = 0.f, x1 = 0.f, y1 = 0.f;
        float x2 = 0.f, y2 = 0.f, x3 = 0.f, y3 = 0.f;
        for (int d = 0; d < Dm; d += 4) {
            const float w0 = wo[d + 0], w1 = wo[d + 1], w2 = wo[d + 2], w3 = wo[d + 3];
            const float2 v0 = *(const float2*)(Wdec + (size_t)(d + 0) * Dm + t0);
            const float2 v1 = *(const float2*)(Wdec + (size_t)(d + 1) * Dm + t0);
            const float2 v2 = *(const float2*)(Wdec + (size_t)(d + 2) * Dm + t0);
            const float2 v3 = *(const float2*)(Wdec + (size_t)(d + 3) * Dm + t0);
            x0 = fmaf(w0, v0.x, x0); y0 = fmaf(w0, v0.y, y0);
            x1 = fmaf(w1, v1.x, x1); y1 = fmaf(w1, v1.y, y1);
            x2 = fmaf(w2, v2.x, x2); y2 = fmaf(w2, v2.y, y2);
            x3 = fmaf(w3, v3.x, x3); y3 = fmaf(w3, v3.y, y3);
        }
        Wc2[(size_t)o * Dm + t0]     = (f16)((x0 + x1) + (x2 + x3));
        Wc2[(size_t)o * Dm + t0 + 1] = (f16)((y0 + y1) + (y2 + y3));
        if (threadIdx.x < 64) {
            const int t = threadIdx.x;
            float p = 0.f;
#pragma unroll
            for (int j = 0; j < 8; ++j)
                p = fmaf(wo[t + 64 * j], b_dec[t + 64 * j], p);
#pragma unroll
            for (int off = 32; off > 0; off >>= 1) p += __shfl_down(p, off);
            if (t == 0) bc2[o] = p + b_out[o];
        }
    } else {
        const int n = blockIdx.x * 256 + threadIdx.x;
        if (blockIdx.x >= 2 || n >= Dm) return;
        const float a   = fmaxf(A_diag[n], 0.f);
        const float dt  = 1.f / (1.f + expf(-log_steps[n]));
        const float d2a = dt * dt * a;
        const float S   = 1.f / (1.f + d2a);
        const float m11 = 1.f - d2a * S;
        const float m12 = -dt * a * S;
        const float m21 = dt * S;
        const float m22 = S;
        cst[n]            = m11;
        cst[Dm + n]       = m12;
        cst[2 * Dm + n]   = m21;
        cst[3 * Dm + n]   = m22;
        cst[4 * Dm + n]   = m11 * dt;
        cst[5 * Dm + n]   = m21 * dt;
        const int j = n >> 6, loc = n & 63;
        BG[(j << 7) + loc]      = gb1[n];   // interleaved [b1|b2] per 64-col group
        BG[(j << 7) + 64 + loc] = gb2[n];
    }
}

// ---------------- fused MFMA GEMM (BMx128 tile, BK=64, counted-vmcnt 2ph) ----
// KM=0: C = A@W^T + bias
// KM=1: C = gelu( A@W^T + DV[col]*EX[row,col] )
// KM=5: W is col-interleaved [w1|w2] per 64-col group; epilogue computes
//       h2 = EX + (P1+b1)*sigmoid(P2+b2) via LDS exchange; writes [M,512] f16
template <int KM, int OUTF16, int BM>
__global__ __launch_bounds__(256, 2) void gemm_mfma(
    const f16* __restrict__ A, const f16* __restrict__ W,
    const float* __restrict__ bias,
    const f16* __restrict__ EX, const float* __restrict__ DV,
    void* __restrict__ Cout, int M, int N, int K)
{
    constexpr int MR   = BM / 32;         // 16x16 frag rows per wave
    constexpr int AELE = BM * 64;         // A tile f16 count
    constexpr int BELE = 128 * 64;        // B tile f16 count
    __shared__ f16 smem[2 * (AELE + BELE)];

    const int tid = threadIdx.x;
    const int l   = tid & 63;
    const int wid = tid >> 6;
    const int wr  = wid >> 1;             // row half
    const int wc  = wid & 1;              // col half
    const int lc  = l & 15;
    const int lr  = l >> 4;
    const int row0 = blockIdx.x * BM;
    const int col0 = blockIdx.y * 128;

    const int NT = K >> 6;
    const int swz  = (l & 7) << 4;
    const int off0 = ((lr * 16) ^ swz) >> 1;
    const int off1 = ((64 + lr * 16) ^ swz) >> 1;

    f32x4 acc[MR][4];
#pragma unroll
    for (int i = 0; i < MR; ++i)
#pragma unroll
        for (int j = 0; j < 4; ++j) acc[i][j] = (f32x4){0.f, 0.f, 0.f, 0.f};

    auto stage_a = [&](f16* dst, const f16* src, int rs) {
#pragma unroll
        for (int c = 0; c < MR; ++c) {
            const int chunk = c * 256 + tid;
            const int row   = chunk >> 3;
            const int kb    = ((chunk & 7) << 4) ^ ((row & 7) << 4);
            gld16(src + (size_t)row * rs + (kb >> 1), dst + chunk * 8);
        }
    };
    auto stage_b = [&](f16* dst, const f16* src, int rs) {
#pragma unroll
        for (int c = 0; c < 4; ++c) {
            const int chunk = c * 256 + tid;
            const int row   = chunk >> 3;
            const int kb    = ((chunk & 7) << 4) ^ ((row & 7) << 4);
            gld16(src + (size_t)row * rs + (kb >> 1), dst + chunk * 8);
        }
    };
    auto compute = [&](const f16* As, const f16* Bs) {
#pragma unroll
        for (int ks = 0; ks < 2; ++ks) {
            const int off = ks ? off1 : off0;
            f16x8 aF[MR], bF[4];
#pragma unroll
            for (int mi = 0; mi < MR; ++mi)
                aF[mi] = *(const f16x8*)(As + (wr * (BM / 2) + mi * 16 + lc) * 64 + off);
#pragma unroll
            for (int ni = 0; ni < 4; ++ni)
                bF[ni] = *(const f16x8*)(Bs + (wc * 64 + ni * 16 + lc) * 64 + off);
#pragma unroll
            for (int mi = 0; mi < MR; ++mi)
#pragma unroll
                for (int ni = 0; ni < 4; ++ni)
                    acc[mi][ni] = __builtin_amdgcn_mfma_f32_16x16x32_f16(
                        aF[mi], bF[ni], acc[mi][ni], 0, 0, 0);
        }
    };

    // ---- counted-vmcnt double-buffered pipeline (fence-hardened) ----
    stage_a(smem, A + (size_t)row0 * K, K);
    stage_b(smem + 2 * AELE, W + (size_t)col0 * K, K);
    int cur = 0;
    for (int kt = 0; kt < NT; ++kt) {
        if (kt + 1 < NT) {
            const int k1 = (kt + 1) << 6;
            stage_a(smem + (cur ^ 1) * AELE, A + (size_t)row0 * K + k1, K);
            stage_b(smem + 2 * AELE + (cur ^ 1) * BELE, W + (size_t)col0 * K + k1, K);
            // wait for the CURRENT tile (oldest MR+4 per-wave loads); prefetch stays in flight
            if constexpr (MR == 2)      asm volatile("s_waitcnt vmcnt(6)" ::: "memory");
            else if constexpr (MR == 1) asm volatile("s_waitcnt vmcnt(5)" ::: "memory");
            else                        asm volatile("s_waitcnt vmcnt(8)" ::: "memory");
        } else {
            asm volatile("s_waitcnt vmcnt(0)" ::: "memory");
        }
        __builtin_amdgcn_sched_barrier(0);
        hard_barrier();                      // all waves' current-tile loads landed
        compute(smem + cur * AELE, smem + 2 * AELE + cur * BELE);
        hard_barrier();                      // all reads of buf[cur] done before overwrite
        cur ^= 1;
    }

    // ---------------- epilogue ----------------
    float* Cf32 = (float*)Cout;
    f16*   Cf16 = (f16*)Cout;
    if constexpr (KM == 5) {
        // GLU combine: wc=1 waves hold P2 cols, wc=0 hold P1 cols (same 64 h-cols)
        float* sig = (float*)smem;  // [BM][65] padded
        __syncthreads();
        if (wc == 1) {
#pragma unroll
            for (int mi = 0; mi < MR; ++mi)
#pragma unroll
                for (int ni = 0; ni < 4; ++ni) {
                    const int col = col0 + 64 + ni * 16 + lc;
                    const int rl0 = wr * (BM / 2) + mi * 16 + lr * 4;
                    const f32x4 v = acc[mi][ni];
#pragma unroll
                    for (int r = 0; r < 4; ++r)
                        sig[(rl0 + r) * 65 + ni * 16 + lc] = sigmoid_f(v[r] + bias[col]);
                }
        }
        __syncthreads();
        if (wc == 0) {
#pragma unroll
            for (int mi = 0; mi < MR; ++mi)
#pragma unroll
                for (int ni = 0; ni < 4; ++ni) {
                    const int cl   = ni * 16 + lc;
                    const int col  = col0 + cl;              // bias index (interleaved)
                    const int hcol = blockIdx.y * 64 + cl;   // h2 column in [0,512)
                    const int rl0  = wr * (BM / 2) + mi * 16 + lr * 4;
                    const f32x4 v = acc[mi][ni];
#pragma unroll
                    for (int r = 0; r < 4; ++r) {
                        const int row = row0 + rl0 + r;
                        const float o = (float)EX[(size_t)row * Dm + hcol]
                                      + (v[r] + bias[col]) * sig[(rl0 + r) * 65 + cl];
                        Cf16[(size_t)row * Dm + hcol] = (f16)o;
                    }
                }
        }
        return;
    }
#pragma unroll
    for (int mi = 0; mi < MR; ++mi) {
#pragma unroll
        for (int ni = 0; ni < 4; ++ni) {
            const int col   = col0 + wc * 64 + ni * 16 + lc;
            const int rbase = row0 + wr * (BM / 2) + mi * 16 + lr * 4;
            const f32x4 v = acc[mi][ni];
            if (KM == 1) {
                const float dv = DV[col];
#pragma unroll
                for (int r = 0; r < 4; ++r) {
                    const size_t idx = (size_t)(rbase + r) * N + col;
                    const float o = gelu_tanh_f(v[r] + dv * (float)EX[idx]);
                    if (OUTF16) Cf16[idx] = (f16)o; else Cf32[idx] = o;
                }
            } else {
                const float bv = bias ? bias[col] : 0.f;
#pragma unroll
                for (int r = 0; r < 4; ++r) {
                    const float o = v[r] + bv;
                    const size_t idx = (size_t)(rbase + r) * N + col;
                    if (OUTF16) Cf16[idx] = (f16)o; else Cf32[idx] = o;
                }
            }
        }
    }
}

// ---------------- LayerNorm (rows of 512, f16 in/out) ----------------
__global__ __launch_bounds__(256) void layernorm_f16(
    const f16* __restrict__ X, const float* __restrict__ g,
    const float* __restrict__ b, f16* __restrict__ Y)
{
    const int lane = threadIdx.x & 63;
    const int w    = threadIdx.x >> 6;
    const int row  = blockIdx.x * 4 + w;
    const size_t base = (size_t)row * Dm + lane * 8;

    const f16x8 v = *(const f16x8*)(X + base);
    float x[8];
    float s = 0.f, q = 0.f;
#pragma unroll
    for (int i = 0; i < 8; ++i) {
        x[i] = (float)v[i];
        s += x[i]; q += x[i] * x[i];
    }
#pragma unroll
    for (int off = 32; off > 0; off >>= 1) {
        s += __shfl_xor(s, off);
        q += __shfl_xor(q, off);
    }
    const float mu  = s * (1.f / 512.f);
    const float var = q * (1.f / 512.f) - mu * mu;
    const float rs  = rsqrtf(var + 1e-5f);

    const float4 g0 = *(const float4*)(g + lane * 8);
    const float4 g1 = *(const float4*)(g + lane * 8 + 4);
    const float4 b0 = *(const float4*)(b + lane * 8);
    const float4 b1 = *(const float4*)(b + lane * 8 + 4);
    const float gg[8] = {g0.x, g0.y, g0.z, g0.w, g1.x, g1.y, g1.z, g1.w};
    const float bb[8] = {b0.x, b0.y, b0.z, b0.w, b1.x, b1.y, b1.z, b1.w};
    f16x8 o;
#pragma unroll
    for (int i = 0; i < 8; ++i)
        o[i] = (f16)((x[i] - mu) * rs * gg[i] + bb[i]);
    *(f16x8*)(Y + base) = o;
}

// ---------------- scan phase 1 (interleaved [re|im] rows of SD) --------------
__global__ __launch_bounds__(512) void scan_phase1(
    const f16* __restrict__ BU, const float* __restrict__ cst,
    float* __restrict__ S1)
{
    const int n = threadIdx.x;
    const int c = blockIdx.x & (NC - 1);
    const int b = blockIdx.x >> 5;
    const float m11 = cst[n],          m12 = cst[Dm + n];
    const float m21 = cst[2 * Dm + n], m22 = cst[3 * Dm + n];
    const float c1  = cst[4 * Dm + n], c2  = cst[5 * Dm + n];

    float zr = 0.f, xr = 0.f, zi = 0.f, xi = 0.f;
    const size_t base = ((size_t)b * Ll + (size_t)c * CL) * SD + n;
#pragma unroll 4
    for (int t = 0; t < CL; ++t) {
        const float br = (float)BU[base + (size_t)t * SD];
        const float bi = (float)BU[base + (size_t)t * SD + 512];
        const float zrn = fmaf(m11, zr, fmaf(m12, xr, c1 * br));
        const float xrn = fmaf(m21, zr, fmaf(m22, xr, c2 * br));
        const float zin = fmaf(m11, zi, fmaf(m12, xi, c1 * bi));
        const float xin = fmaf(m21, zi, fmaf(m22, xi, c2 * bi));
        zr = zrn; xr = xrn; zi = zin; xi = xin;
    }
    const int idx = blockIdx.x * Dm + n;
    S1[idx]            = zr;
    S1[SZ1 + idx]      = xr;
    S1[2 * SZ1 + idx]  = zi;
    S1[3 * SZ1 + idx]  = xi;
}

// ---------------- scan phase 2 ----------------
__global__ __launch_bounds__(256) void scan_phase2(
    const float* __restrict__ S1, const float* __restrict__ cst,
    float* __restrict__ G)
{
    const int gidx = blockIdx.x * 256 + threadIdx.x; // 0..4095
    const int n = gidx & (Dm - 1);
    const int b = gidx >> 9;
    const float m11 = cst[n],          m12 = cst[Dm + n];
    const float m21 = cst[2 * Dm + n], m22 = cst[3 * Dm + n];

    float p11 = 1.f, p12 = 0.f, p21 = 0.f, p22 = 1.f;
    for (int i = 0; i < CL; ++i) {
        const float q11 = m11 * p11 + m12 * p21;
        const float q12 = m11 * p12 + m12 * p22;
        const float q21 = m21 * p11 + m22 * p21;
        const float q22 = m21 * p12 + m22 * p22;
        p11 = q11; p12 = q12; p21 = q21; p22 = q22;
    }

    float gzr = 0.f, gxr = 0.f, gzi = 0.f, gxi = 0.f;
    for (int c = 0; c < NC; ++c) {
        const int idx = (b * NC + c) * Dm + n;
        G[idx]           = gzr;
        G[SZ1 + idx]     = gxr;
        G[2 * SZ1 + idx] = gzi;
        G[3 * SZ1 + idx] = gxi;
        const float szr = S1[idx],           sxr = S1[SZ1 + idx];
        const float szi = S1[2 * SZ1 + idx], sxi = S1[3 * SZ1 + idx];
        const float t1 = p11 * gzr + p12 * gxr + szr;
        const float t2 = p21 * gzr + p22 * gxr + sxr;
        const float t3 = p11 * gzi + p12 * gxi + szi;
        const float t4 = p21 * gzi + p22 * gxi + sxi;
        gzr = t1; gxr = t2; gzi = t3; gxi = t4;
    }
}

// ---------------- scan phase 3: re-scan; XS = [xr | -xi] interleaved ---------
__global__ __launch_bounds__(512) void scan_phase3(
    const f16* __restrict__ BU, const float* __restrict__ cst,
    const float* __restrict__ G, f16* __restrict__ XS)
{
    const int n = threadIdx.x;
    const int c = blockIdx.x & (NC - 1);
    const int b = blockIdx.x >> 5;
    const float m11 = cst[n],          m12 = cst[Dm + n];
    const float m21 = cst[2 * Dm + n], m22 = cst[3 * Dm + n];
    const float c1  = cst[4 * Dm + n], c2  = cst[5 * Dm + n];

    const int sidx = blockIdx.x * Dm + n;
    float zr = G[sidx];
    float xr = G[SZ1 + sidx];
    float zi = G[2 * SZ1 + sidx];
    float xi = G[3 * SZ1 + sidx];

    const size_t base = ((size_t)b * Ll + (size_t)c * CL) * SD + n;
#pragma unroll 4
    for (int t = 0; t < CL; ++t) {
        const float br = (float)BU[base + (size_t)t * SD];
        const float bi = (float)BU[base + (size_t)t * SD + 512];
        const float zrn = fmaf(m11, zr, fmaf(m12, xr, c1 * br));
        const float xrn = fmaf(m21, zr, fmaf(m22, xr, c2 * br));
        const float zin = fmaf(m11, zi, fmaf(m12, xi, c1 * bi));
        const float xin = fmaf(m21, zi, fmaf(m22, xi, c2 * bi));
        zr = zrn; xr = xrn; zi = zin; xi = xin;
        XS[base + (size_t)t * SD]       = (f16)xr;
        XS[base + (size_t)t * SD + 512] = (f16)(-xi);
    }
}

// ---------------- launch ----------------
extern "C" void kernel_launch(void* const* d_in, const int* in_sizes, int n_in,
                              void* d_out, int out_size, void* d_ws, size_t ws_size,
                              hipStream_t stream)
{
    const float* x         = (const float*)d_in[0];
    const float* W_in      = (const float*)d_in[1];
    const float* b_in      = (const float*)d_in[2];
    const float* W_enc     = (const float*)d_in[3];
    const float* b_enc     = (const float*)d_in[4];
    const float* ln_g      = (const float*)d_in[5];
    const float* ln_b      = (const float*)d_in[6];
    const float* A_diag    = (const float*)d_in[7];
    const float* log_steps = (const float*)d_in[8];
    const float* B_re      = (const float*)d_in[9];
    const float* B_im      = (const float*)d_in[10];
    const float* C_re      = (const float*)d_in[11];
    const float* C_im      = (const float*)d_in[12];
    const float* Dv        = (const float*)d_in[13];
    const float* glu_w1    = (const float*)d_in[14];
    const float* glu_b1    = (const float*)d_in[15];
    const float* glu_w2    = (const float*)d_in[16];
    const float* glu_b2    = (const float*)d_in[17];
    const float* W_dec     = (const float*)d_in[18];
    const float* b_dec     = (const float*)d_in[19];
    const float* W_out     = (const float*)d_in[20];
    const float* b_out     = (const float*)d_in[21];

    char* ws = (char*)d_ws;
    const size_t MB = 1 << 20;
    f16*   F2  = (f16*)(ws);             // skip f16 [M,512]
    f16*   F3  = (f16*)(ws + 16 * MB);   // hn f16 [M,512]; later h2
    f16*   XS  = (f16*)(ws + 32 * MB);   // [M,1024] = [xr | -xi]
    f16*   BU  = (f16*)(ws + 64 * MB);   // [M,1024] = [BuR | BuI]
    f16*   GF  = (f16*)(ws + 96 * MB);   // g f16 [M,512]
    f16*   XF  = (f16*)(ws + 112 * MB);  // x f16 [M,128] (4 MB)
    float* S1  = (float*)(ws + 116 * MB);
    float* G   = (float*)(ws + 118 * MB);
    float* cst = (float*)(ws + 120 * MB);
    float* BG  = (float*)(ws + 120 * MB + 64 * 1024);   // interleaved [b1|b2]
    float* bc1 = (float*)(ws + 120 * MB + 128 * 1024);
    float* bc2 = (float*)(ws + 120 * MB + 192 * 1024);
    f16*   WB  = (f16*)(ws + 121 * MB);  // [1024][512] = [B_re; B_im]
    f16*   WC  = (f16*)(ws + 122 * MB);  // [512][1024] = [C_re | C_im]
    f16*   WG  = (f16*)(ws + 123 * MB);  // [1024][512] = interleaved [w1|w2] per 64
    f16*   Wc1 = (f16*)(ws + 124 * MB);  // [512][128]
    f16*   Wc2 = (f16*)(ws + 124 * MB + 256 * 1024);  // [128][512]

    CvtJobs jobs;
    jobs.j[0] = {x,      XF,            Mrows * Hin, 7, Hin,  0,   0};
    jobs.j[1] = {B_re,   WB,            Dm * Dm,     9, Dm,   0,   0};
    jobs.j[2] = {B_im,   WB + 512 * Dm, Dm * Dm,     9, Dm,   0,   0};
    jobs.j[3] = {C_re,   WC,            Dm * Dm,     9, 1024, 0,   0};
    jobs.j[4] = {C_im,   WC,            Dm * Dm,     9, 1024, 512, 0};
    jobs.j[5] = {glu_w1, WG,            Dm * Dm,     9, Dm,   0,   1};
    jobs.j[6] = {glu_w2, WG,            Dm * Dm,     9, Dm,   64,  1};

    prep_k<<<dim3(512, 10), 256, 0, stream>>>(
        jobs, W_enc, W_in, b_in, b_enc, W_out, W_dec, b_dec, b_out,
        A_diag, log_steps, glu_b1, glu_b2, Wc1, bc1, Wc2, bc2, cst, BG);

    dim3 blk(256);

    // skip = x @ Wc1^T + bc1   (K=128, N=512)
    gemm_mfma<0, 1, 64><<<dim3(Mrows / 64, 4), blk, 0, stream>>>(
        XF, Wc1, bc1, nullptr, nullptr, F2, Mrows, Dm, Hin);
    // hn = layernorm(skip)
    layernorm_f16<<<Mrows / 4, 256, 0, stream>>>(F2, ln_g, ln_b, F3);
    // BU = hn @ [B_re;B_im]^T   (K=512, N=1024)
    gemm_mfma<0, 1, 64><<<dim3(Mrows / 64, 8), blk, 0, stream>>>(
        F3, WB, nullptr, nullptr, nullptr, BU, Mrows, 1024, Dm);
    // LinOSS scan (fp32 state)
    scan_phase1<<<Bb * NC, 512, 0, stream>>>(BU, cst, S1);
    scan_phase2<<<(Bb * Dm) / 256, 256, 0, stream>>>(S1, cst, G);
    scan_phase3<<<Bb * NC, 512, 0, stream>>>(BU, cst, G, XS);
    // g = gelu(XS @ WC^T + D*hn)   (K=1024, N=512)
    gemm_mfma<1, 1, 64><<<dim3(Mrows / 64, 4), blk, 0, stream>>>(
        XS, WC, nullptr, F3, Dv, GF, Mrows, Dm, 1024);
    // h2 = skip + (g@w1^T+b1)*sigmoid(g@w2^T+b2)  (K=512, interleaved N=1024 -> h2[M,512])
    gemm_mfma<5, 1, 64><<<dim3(Mrows / 64, 8), blk, 0, stream>>>(
        GF, WG, BG, F2, nullptr, F3, Mrows, 1024, Dm);
    // out = h2 @ Wc2^T + bc2   (K=512, N=128, fp32 out)
    gemm_mfma<0, 0, 32><<<dim3(Mrows / 32, 1), blk, 0, stream>>>(
        F3, Wc2, bc2, nullptr, nullptr, (float*)d_out, Mrows, Hin, Dm);
}

// Round 12
// 277.273 us; speedup vs baseline: 1.4455x; 1.0712x over previous
//
#include <hip/hip_runtime.h>
#include <cstddef>
#include <cstdint>
#include <math.h>

typedef _Float16 f16;
typedef f16 f16x8 __attribute__((ext_vector_type(8)));
typedef f16 f16x4 __attribute__((ext_vector_type(4)));
typedef float f32x4 __attribute__((ext_vector_type(4)));

// ---------------- problem constants ----------------
constexpr int Bb   = 8;
constexpr int Ll   = 2048;
constexpr int Hin  = 128;
constexpr int Dm   = 512;
constexpr int Mrows = Bb * Ll;          // 16384
constexpr int NC   = 64;                // scan chunks per sequence
constexpr int CL   = Ll / NC;           // 32 timesteps per chunk
constexpr int SZ1  = Bb * NC * Dm;      // 262144 per state component
constexpr int SD   = 1024;              // interleaved [re|im] row stride

// ---------------- device math helpers ----------------
static __device__ __forceinline__ float sigmoid_f(float x) {
    return 1.f / (1.f + expf(-x));
}
static __device__ __forceinline__ float gelu_tanh_f(float x) {
    float x3 = x * x * x;
    float t  = tanhf(0.7978845608028654f * (x + 0.044715f * x3));
    return 0.5f * x * (1.f + t);
}

// async global->LDS, 16 bytes per lane (linear LDS dest: wave base + lane*16)
static __device__ __forceinline__ void gld16(const f16* g, f16* l) {
    __builtin_amdgcn_global_load_lds(
        (const __attribute__((address_space(1))) void*)g,
        (__attribute__((address_space(3))) void*)l, 16, 0, 0);
}

// hard barrier: real compiler memory fence + HW barrier
static __device__ __forceinline__ void hard_barrier() {
    __builtin_amdgcn_sched_barrier(0);
    asm volatile("s_barrier" ::: "memory");
    __builtin_amdgcn_sched_barrier(0);
}

// ---------------- unified prep kernel ----------------
// y<9 : fp32->f16 convert jobs (optionally row-interleaved for GLU weights)
// y=9 : transpose-convert Win [512][128] -> WinT [128][512] f16
// y=10: transpose-convert Wdec [512][512] -> WdecT [512][512] f16
// y=11: bias reductions bc1 (blocks 0..127), bc2 (blocks 128..159), wave-per-output
// y=12: scan constants + interleaved GLU bias
struct CvtJob { const float* s; f16* d; int n; int lgL; int pitch; int off; int ilv; };
struct CvtJobs { CvtJob j[9]; };

__global__ __launch_bounds__(256) void prep_k(
    CvtJobs jobs,
    const float* __restrict__ Wenc, const float* __restrict__ Win,
    const float* __restrict__ b_in, const float* __restrict__ b_enc,
    const float* __restrict__ Wout, const float* __restrict__ Wdec,
    const float* __restrict__ b_dec, const float* __restrict__ b_out,
    const float* __restrict__ A_diag, const float* __restrict__ log_steps,
    const float* __restrict__ gb1, const float* __restrict__ gb2,
    f16* __restrict__ WinT, f16* __restrict__ WdecT,
    float* __restrict__ bc1, float* __restrict__ bc2,
    float* __restrict__ cst, float* __restrict__ BG)
{
    __shared__ float tile[64][65];
    const int y = blockIdx.y;
    if (y < 9) {
        const CvtJob jb = jobs.j[y];
        const int mask = (1 << jb.lgL) - 1;
        for (int i = (blockIdx.x * 256 + threadIdx.x) * 4; i < jb.n; i += 512 * 256 * 4) {
            const float4 v = *(const float4*)(jb.s + i);
            const int row = i >> jb.lgL;
            const int c   = i & mask;
            f16* dp = jb.ilv
                ? jb.d + (size_t)(((row >> 6) << 7) + (row & 63) + jb.off) * jb.pitch + c
                : jb.d + (size_t)row * jb.pitch + jb.off + c;
            f16x4 o;
            o.x = (f16)v.x; o.y = (f16)v.y; o.z = (f16)v.z; o.w = (f16)v.w;
            *(f16x4*)dp = o;
        }
    } else if (y == 9 || y == 10) {
        // 64x64 tiled transpose-convert
        const int LW   = (y == 9) ? Hin : Dm;        // source row length
        const float* S = (y == 9) ? Win : Wdec;
        f16* D         = (y == 9) ? WinT : WdecT;
        const int NTIL = (y == 9) ? 16 : 64;         // (512/64) x (LW/64)
        const int CT   = LW >> 6;                    // col tiles
        if (blockIdx.x >= NTIL) return;
        const int tr = blockIdx.x / CT, tc = blockIdx.x % CT;
        const int r0 = tr * 64, c0 = tc * 64;
        const int tid = threadIdx.x;
#pragma unroll
        for (int i = 0; i < 4; ++i) {
            const int r  = (tid >> 4) + i * 16;
            const int c4 = (tid & 15) * 4;
            const float4 v = *(const float4*)(S + (size_t)(r0 + r) * LW + c0 + c4);
            tile[r][c4 + 0] = v.x; tile[r][c4 + 1] = v.y;
            tile[r][c4 + 2] = v.z; tile[r][c4 + 3] = v.w;
        }
        __syncthreads();
#pragma unroll
        for (int i = 0; i < 4; ++i) {
            const int c  = (tid >> 4) + i * 16;
            const int r4 = (tid & 15) * 4;
            f16x4 o;
            o.x = (f16)tile[r4 + 0][c]; o.y = (f16)tile[r4 + 1][c];
            o.z = (f16)tile[r4 + 2][c]; o.w = (f16)tile[r4 + 3][c];
            *(f16x4*)(D + (size_t)(c0 + c) * 512 + r0 + r4) = o;
        }
    } else if (y == 11) {
        // wave-per-output bias reductions
        const int w    = threadIdx.x >> 6;
        const int lane = threadIdx.x & 63;
        if (blockIdx.x < 128) {
            const int d2 = blockIdx.x * 4 + w;
            const float* wr = Wenc + (size_t)d2 * Dm;
            float p = 0.f;
#pragma unroll
            for (int j = 0; j < 8; ++j)
                p = fmaf(wr[lane + 64 * j], b_in[lane + 64 * j], p);
#pragma unroll
            for (int off = 32; off > 0; off >>= 1) p += __shfl_down(p, off);
            if (lane == 0) bc1[d2] = p + b_enc[d2];
        } else if (blockIdx.x < 160) {
            const int o = (blockIdx.x - 128) * 4 + w;
            const float* wo = Wout + (size_t)o * Dm;
            float p = 0.f;
#pragma unroll
            for (int j = 0; j < 8; ++j)
                p = fmaf(wo[lane + 64 * j], b_dec[lane + 64 * j], p);
#pragma unroll
            for (int off = 32; off > 0; off >>= 1) p += __shfl_down(p, off);
            if (lane == 0) bc2[o] = p + b_out[o];
        }
    } else if (y == 12) {
        const int n = blockIdx.x * 256 + threadIdx.x;
        if (blockIdx.x >= 2 || n >= Dm) return;
        const float a   = fmaxf(A_diag[n], 0.f);
        const float dt  = 1.f / (1.f + expf(-log_steps[n]));
        const float d2a = dt * dt * a;
        const float S   = 1.f / (1.f + d2a);
        const float m11 = 1.f - d2a * S;
        const float m12 = -dt * a * S;
        const float m21 = dt * S;
        const float m22 = S;
        cst[n]            = m11;
        cst[Dm + n]       = m12;
        cst[2 * Dm + n]   = m21;
        cst[3 * Dm + n]   = m22;
        cst[4 * Dm + n]   = m11 * dt;
        cst[5 * Dm + n]   = m21 * dt;
        const int j = n >> 6, loc = n & 63;
        BG[(j << 7) + loc]      = gb1[n];   // interleaved [b1|b2] per 64-col group
        BG[(j << 7) + 64 + loc] = gb2[n];
    }
}

// ---------------- fused MFMA GEMM (BMx128 tile, BK=64, counted-vmcnt 2ph) ----
// KM=0: C = A@W^T + bias
// KM=1: C = gelu( A@W^T + DV[col]*EX[row,col] )
// KM=5: W is col-interleaved [w1|w2] per 64-col group; epilogue computes
//       h2 = EX + (P1+b1)*sigmoid(P2+b2) via LDS exchange; writes [M,512] f16
template <int KM, int OUTF16, int BM>
__global__ __launch_bounds__(256, 2) void gemm_mfma(
    const f16* __restrict__ A, const f16* __restrict__ W,
    const float* __restrict__ bias,
    const f16* __restrict__ EX, const float* __restrict__ DV,
    void* __restrict__ Cout, int M, int N, int K)
{
    constexpr int MR   = BM / 32;         // 16x16 frag rows per wave
    constexpr int AELE = BM * 64;         // A tile f16 count
    constexpr int BELE = 128 * 64;        // B tile f16 count
    __shared__ f16 smem[2 * (AELE + BELE)];

    const int tid = threadIdx.x;
    const int l   = tid & 63;
    const int wid = tid >> 6;
    const int wr  = wid >> 1;             // row half
    const int wc  = wid & 1;              // col half
    const int lc  = l & 15;
    const int lr  = l >> 4;
    const int row0 = blockIdx.x * BM;
    const int col0 = blockIdx.y * 128;

    const int NT = K >> 6;
    const int swz  = (l & 7) << 4;
    const int off0 = ((lr * 16) ^ swz) >> 1;
    const int off1 = ((64 + lr * 16) ^ swz) >> 1;

    f32x4 acc[MR][4];
#pragma unroll
    for (int i = 0; i < MR; ++i)
#pragma unroll
        for (int j = 0; j < 4; ++j) acc[i][j] = (f32x4){0.f, 0.f, 0.f, 0.f};

    auto stage_a = [&](f16* dst, const f16* src, int rs) {
#pragma unroll
        for (int c = 0; c < MR; ++c) {
            const int chunk = c * 256 + tid;
            const int row   = chunk >> 3;
            const int kb    = ((chunk & 7) << 4) ^ ((row & 7) << 4);
            gld16(src + (size_t)row * rs + (kb >> 1), dst + chunk * 8);
        }
    };
    auto stage_b = [&](f16* dst, const f16* src, int rs) {
#pragma unroll
        for (int c = 0; c < 4; ++c) {
            const int chunk = c * 256 + tid;
            const int row   = chunk >> 3;
            const int kb    = ((chunk & 7) << 4) ^ ((row & 7) << 4);
            gld16(src + (size_t)row * rs + (kb >> 1), dst + chunk * 8);
        }
    };
    auto compute = [&](const f16* As, const f16* Bs) {
#pragma unroll
        for (int ks = 0; ks < 2; ++ks) {
            const int off = ks ? off1 : off0;
            f16x8 aF[MR], bF[4];
#pragma unroll
            for (int mi = 0; mi < MR; ++mi)
                aF[mi] = *(const f16x8*)(As + (wr * (BM / 2) + mi * 16 + lc) * 64 + off);
#pragma unroll
            for (int ni = 0; ni < 4; ++ni)
                bF[ni] = *(const f16x8*)(Bs + (wc * 64 + ni * 16 + lc) * 64 + off);
#pragma unroll
            for (int mi = 0; mi < MR; ++mi)
#pragma unroll
                for (int ni = 0; ni < 4; ++ni)
                    acc[mi][ni] = __builtin_amdgcn_mfma_f32_16x16x32_f16(
                        aF[mi], bF[ni], acc[mi][ni], 0, 0, 0);
        }
    };

    // ---- counted-vmcnt double-buffered pipeline (fence-hardened) ----
    stage_a(smem, A + (size_t)row0 * K, K);
    stage_b(smem + 2 * AELE, W + (size_t)col0 * K, K);
    int cur = 0;
    for (int kt = 0; kt < NT; ++kt) {
        if (kt + 1 < NT) {
            const int k1 = (kt + 1) << 6;
            stage_a(smem + (cur ^ 1) * AELE, A + (size_t)row0 * K + k1, K);
            stage_b(smem + 2 * AELE + (cur ^ 1) * BELE, W + (size_t)col0 * K + k1, K);
            // wait for the CURRENT tile; prefetch stays in flight
            if constexpr (MR == 2)      asm volatile("s_waitcnt vmcnt(6)" ::: "memory");
            else if constexpr (MR == 1) asm volatile("s_waitcnt vmcnt(5)" ::: "memory");
            else                        asm volatile("s_waitcnt vmcnt(8)" ::: "memory");
        } else {
            asm volatile("s_waitcnt vmcnt(0)" ::: "memory");
        }
        __builtin_amdgcn_sched_barrier(0);
        hard_barrier();                      // current-tile loads landed (all waves)
        compute(smem + cur * AELE, smem + 2 * AELE + cur * BELE);
        hard_barrier();                      // reads of buf[cur] done before overwrite
        cur ^= 1;
    }

    // ---------------- epilogue ----------------
    float* Cf32 = (float*)Cout;
    f16*   Cf16 = (f16*)Cout;
    if constexpr (KM == 5) {
        // GLU combine: wc=1 waves hold P2 cols, wc=0 hold P1 cols (same 64 h-cols)
        float* sig = (float*)smem;  // [BM][65] padded
        __syncthreads();
        if (wc == 1) {
#pragma unroll
            for (int mi = 0; mi < MR; ++mi)
#pragma unroll
                for (int ni = 0; ni < 4; ++ni) {
                    const int col = col0 + 64 + ni * 16 + lc;
                    const int rl0 = wr * (BM / 2) + mi * 16 + lr * 4;
                    const f32x4 v = acc[mi][ni];
#pragma unroll
                    for (int r = 0; r < 4; ++r)
                        sig[(rl0 + r) * 65 + ni * 16 + lc] = sigmoid_f(v[r] + bias[col]);
                }
        }
        __syncthreads();
        if (wc == 0) {
#pragma unroll
            for (int mi = 0; mi < MR; ++mi)
#pragma unroll
                for (int ni = 0; ni < 4; ++ni) {
                    const int cl   = ni * 16 + lc;
                    const int col  = col0 + cl;              // bias index (interleaved)
                    const int hcol = blockIdx.y * 64 + cl;   // h2 column in [0,512)
                    const int rl0  = wr * (BM / 2) + mi * 16 + lr * 4;
                    const f32x4 v = acc[mi][ni];
#pragma unroll
                    for (int r = 0; r < 4; ++r) {
                        const int row = row0 + rl0 + r;
                        const float o = (float)EX[(size_t)row * Dm + hcol]
                                      + (v[r] + bias[col]) * sig[(rl0 + r) * 65 + cl];
                        Cf16[(size_t)row * Dm + hcol] = (f16)o;
                    }
                }
        }
        return;
    }
#pragma unroll
    for (int mi = 0; mi < MR; ++mi) {
#pragma unroll
        for (int ni = 0; ni < 4; ++ni) {
            const int col   = col0 + wc * 64 + ni * 16 + lc;
            const int rbase = row0 + wr * (BM / 2) + mi * 16 + lr * 4;
            const f32x4 v = acc[mi][ni];
            if (KM == 1) {
                const float dv = DV[col];
#pragma unroll
                for (int r = 0; r < 4; ++r) {
                    const size_t idx = (size_t)(rbase + r) * N + col;
                    const float o = gelu_tanh_f(v[r] + dv * (float)EX[idx]);
                    if (OUTF16) Cf16[idx] = (f16)o; else Cf32[idx] = o;
                }
            } else {
                const float bv = bias ? bias[col] : 0.f;
#pragma unroll
                for (int r = 0; r < 4; ++r) {
                    const float o = v[r] + bv;
                    const size_t idx = (size_t)(rbase + r) * N + col;
                    if (OUTF16) Cf16[idx] = (f16)o; else Cf32[idx] = o;
                }
            }
        }
    }
}

// ---------------- LayerNorm (rows of 512, f16 in/out) ----------------
__global__ __launch_bounds__(256) void layernorm_f16(
    const f16* __restrict__ X, const float* __restrict__ g,
    const float* __restrict__ b, f16* __restrict__ Y)
{
    const int lane = threadIdx.x & 63;
    const int w    = threadIdx.x >> 6;
    const int row  = blockIdx.x * 4 + w;
    const size_t base = (size_t)row * Dm + lane * 8;

    const f16x8 v = *(const f16x8*)(X + base);
    float x[8];
    float s = 0.f, q = 0.f;
#pragma unroll
    for (int i = 0; i < 8; ++i) {
        x[i] = (float)v[i];
        s += x[i]; q += x[i] * x[i];
    }
#pragma unroll
    for (int off = 32; off > 0; off >>= 1) {
        s += __shfl_xor(s, off);
        q += __shfl_xor(q, off);
    }
    const float mu  = s * (1.f / 512.f);
    const float var = q * (1.f / 512.f) - mu * mu;
    const float rs  = rsqrtf(var + 1e-5f);

    const float4 g0 = *(const float4*)(g + lane * 8);
    const float4 g1 = *(const float4*)(g + lane * 8 + 4);
    const float4 b0 = *(const float4*)(b + lane * 8);
    const float4 b1 = *(const float4*)(b + lane * 8 + 4);
    const float gg[8] = {g0.x, g0.y, g0.z, g0.w, g1.x, g1.y, g1.z, g1.w};
    const float bb[8] = {b0.x, b0.y, b0.z, b0.w, b1.x, b1.y, b1.z, b1.w};
    f16x8 o;
#pragma unroll
    for (int i = 0; i < 8; ++i)
        o[i] = (f16)((x[i] - mu) * rs * gg[i] + bb[i]);
    *(f16x8*)(Y + base) = o;
}

// ---------------- scan phase 1 (interleaved [re|im] rows of SD) --------------
__global__ __launch_bounds__(512) void scan_phase1(
    const f16* __restrict__ BU, const float* __restrict__ cst,
    float* __restrict__ S1)
{
    const int n = threadIdx.x;
    const int c = blockIdx.x & (NC - 1);
    const int b = blockIdx.x >> 6;
    const float m11 = cst[n],          m12 = cst[Dm + n];
    const float m21 = cst[2 * Dm + n], m22 = cst[3 * Dm + n];
    const float c1  = cst[4 * Dm + n], c2  = cst[5 * Dm + n];

    float zr = 0.f, xr = 0.f, zi = 0.f, xi = 0.f;
    const size_t base = ((size_t)b * Ll + (size_t)c * CL) * SD + n;
#pragma unroll 4
    for (int t = 0; t < CL; ++t) {
        const float br = (float)BU[base + (size_t)t * SD];
        const float bi = (float)BU[base + (size_t)t * SD + 512];
        const float zrn = fmaf(m11, zr, fmaf(m12, xr, c1 * br));
        const float xrn = fmaf(m21, zr, fmaf(m22, xr, c2 * br));
        const float zin = fmaf(m11, zi, fmaf(m12, xi, c1 * bi));
        const float xin = fmaf(m21, zi, fmaf(m22, xi, c2 * bi));
        zr = zrn; xr = xrn; zi = zin; xi = xin;
    }
    const int idx = blockIdx.x * Dm + n;
    S1[idx]            = zr;
    S1[SZ1 + idx]      = xr;
    S1[2 * SZ1 + idx]  = zi;
    S1[3 * SZ1 + idx]  = xi;
}

// ---------------- scan phase 2 ----------------
__global__ __launch_bounds__(256) void scan_phase2(
    const float* __restrict__ S1, const float* __restrict__ cst,
    float* __restrict__ G)
{
    const int gidx = blockIdx.x * 256 + threadIdx.x; // 0..4095
    const int n = gidx & (Dm - 1);
    const int b = gidx >> 9;
    const float m11 = cst[n],          m12 = cst[Dm + n];
    const float m21 = cst[2 * Dm + n], m22 = cst[3 * Dm + n];

    float p11 = 1.f, p12 = 0.f, p21 = 0.f, p22 = 1.f;
    for (int i = 0; i < CL; ++i) {
        const float q11 = m11 * p11 + m12 * p21;
        const float q12 = m11 * p12 + m12 * p22;
        const float q21 = m21 * p11 + m22 * p21;
        const float q22 = m21 * p12 + m22 * p22;
        p11 = q11; p12 = q12; p21 = q21; p22 = q22;
    }

    float gzr = 0.f, gxr = 0.f, gzi = 0.f, gxi = 0.f;
    for (int c = 0; c < NC; ++c) {
        const int idx = (b * NC + c) * Dm + n;
        G[idx]           = gzr;
        G[SZ1 + idx]     = gxr;
        G[2 * SZ1 + idx] = gzi;
        G[3 * SZ1 + idx] = gxi;
        const float szr = S1[idx],           sxr = S1[SZ1 + idx];
        const float szi = S1[2 * SZ1 + idx], sxi = S1[3 * SZ1 + idx];
        const float t1 = p11 * gzr + p12 * gxr + szr;
        const float t2 = p21 * gzr + p22 * gxr + sxr;
        const float t3 = p11 * gzi + p12 * gxi + szi;
        const float t4 = p21 * gzi + p22 * gxi + sxi;
        gzr = t1; gxr = t2; gzi = t3; gxi = t4;
    }
}

// ---------------- scan phase 3: re-scan; XS = [xr | -xi] interleaved ---------
__global__ __launch_bounds__(512) void scan_phase3(
    const f16* __restrict__ BU, const float* __restrict__ cst,
    const float* __restrict__ G, f16* __restrict__ XS)
{
    const int n = threadIdx.x;
    const int c = blockIdx.x & (NC - 1);
    const int b = blockIdx.x >> 6;
    const float m11 = cst[n],          m12 = cst[Dm + n];
    const float m21 = cst[2 * Dm + n], m22 = cst[3 * Dm + n];
    const float c1  = cst[4 * Dm + n], c2  = cst[5 * Dm + n];

    const int sidx = blockIdx.x * Dm + n;
    float zr = G[sidx];
    float xr = G[SZ1 + sidx];
    float zi = G[2 * SZ1 + sidx];
    float xi = G[3 * SZ1 + sidx];

    const size_t base = ((size_t)b * Ll + (size_t)c * CL) * SD + n;
#pragma unroll 4
    for (int t = 0; t < CL; ++t) {
        const float br = (float)BU[base + (size_t)t * SD];
        const float bi = (float)BU[base + (size_t)t * SD + 512];
        const float zrn = fmaf(m11, zr, fmaf(m12, xr, c1 * br));
        const float xrn = fmaf(m21, zr, fmaf(m22, xr, c2 * br));
        const float zin = fmaf(m11, zi, fmaf(m12, xi, c1 * bi));
        const float xin = fmaf(m21, zi, fmaf(m22, xi, c2 * bi));
        zr = zrn; xr = xrn; zi = zin; xi = xin;
        XS[base + (size_t)t * SD]       = (f16)xr;
        XS[base + (size_t)t * SD + 512] = (f16)(-xi);
    }
}

// ---------------- launch ----------------
extern "C" void kernel_launch(void* const* d_in, const int* in_sizes, int n_in,
                              void* d_out, int out_size, void* d_ws, size_t ws_size,
                              hipStream_t stream)
{
    const float* x         = (const float*)d_in[0];
    const float* W_in      = (const float*)d_in[1];
    const float* b_in      = (const float*)d_in[2];
    const float* W_enc     = (const float*)d_in[3];
    const float* b_enc     = (const float*)d_in[4];
    const float* ln_g      = (const float*)d_in[5];
    const float* ln_b      = (const float*)d_in[6];
    const float* A_diag    = (const float*)d_in[7];
    const float* log_steps = (const float*)d_in[8];
    const float* B_re      = (const float*)d_in[9];
    const float* B_im      = (const float*)d_in[10];
    const float* C_re      = (const float*)d_in[11];
    const float* C_im      = (const float*)d_in[12];
    const float* Dv        = (const float*)d_in[13];
    const float* glu_w1    = (const float*)d_in[14];
    const float* glu_b1    = (const float*)d_in[15];
    const float* glu_w2    = (const float*)d_in[16];
    const float* glu_b2    = (const float*)d_in[17];
    const float* W_dec     = (const float*)d_in[18];
    const float* b_dec     = (const float*)d_in[19];
    const float* W_out     = (const float*)d_in[20];
    const float* b_out     = (const float*)d_in[21];

    char* ws = (char*)d_ws;
    const size_t MB = 1 << 20;
    const size_t KB = 1 << 10;
    f16*   F2  = (f16*)(ws);             // skip f16 [M,512]
    f16*   F3  = (f16*)(ws + 16 * MB);   // hn f16 [M,512]; later h2
    f16*   XS  = (f16*)(ws + 32 * MB);   // [M,1024] = [xr | -xi]
    f16*   BU  = (f16*)(ws + 64 * MB);   // [M,1024] = [BuR | BuI]
    f16*   GF  = (f16*)(ws + 96 * MB);   // g f16 [M,512]
    f16*   XF  = (f16*)(ws + 112 * MB);  // x f16 [M,128] (4 MB)
    float* S1  = (float*)(ws + 116 * MB);           // 4 MB (NC=64)
    float* G   = (float*)(ws + 120 * MB);           // 4 MB
    float* cst = (float*)(ws + 124 * MB);
    float* BG  = (float*)(ws + 124 * MB + 64 * KB); // interleaved [b1|b2]
    float* bc1 = (float*)(ws + 124 * MB + 128 * KB);
    float* bc2 = (float*)(ws + 124 * MB + 192 * KB);
    f16*   WB  = (f16*)(ws + 125 * MB);  // [1024][512] = [B_re; B_im]
    f16*   WC  = (f16*)(ws + 126 * MB);  // [512][1024] = [C_re | C_im]
    f16*   WG  = (f16*)(ws + 127 * MB);  // [1024][512] = interleaved [w1|w2] per 64
    f16*   Wc1   = (f16*)(ws + 128 * MB);             // [512][128]
    f16*   Wc2   = (f16*)(ws + 128 * MB + 128 * KB);  // [128][512]
    f16*   WinT  = (f16*)(ws + 128 * MB + 256 * KB);  // [128][512]
    f16*   WoutF = (f16*)(ws + 128 * MB + 384 * KB);  // [128][512]
    f16*   WencF = (f16*)(ws + 128 * MB + 512 * KB);  // [512][512]
    f16*   WdecT = (f16*)(ws + 129 * MB);             // [512][512]

    CvtJobs jobs;
    jobs.j[0] = {x,      XF,            Mrows * Hin, 7, Hin,  0,   0};
    jobs.j[1] = {B_re,   WB,            Dm * Dm,     9, Dm,   0,   0};
    jobs.j[2] = {B_im,   WB + 512 * Dm, Dm * Dm,     9, Dm,   0,   0};
    jobs.j[3] = {C_re,   WC,            Dm * Dm,     9, 1024, 0,   0};
    jobs.j[4] = {C_im,   WC,            Dm * Dm,     9, 1024, 512, 0};
    jobs.j[5] = {glu_w1, WG,            Dm * Dm,     9, Dm,   0,   1};
    jobs.j[6] = {glu_w2, WG,            Dm * Dm,     9, Dm,   64,  1};
    jobs.j[7] = {W_enc,  WencF,         Dm * Dm,     9, Dm,   0,   0};
    jobs.j[8] = {W_out,  WoutF,         Hin * Dm,    9, Dm,   0,   0};

    prep_k<<<dim3(512, 13), 256, 0, stream>>>(
        jobs, W_enc, W_in, b_in, b_enc, W_out, W_dec, b_dec, b_out,
        A_diag, log_steps, glu_b1, glu_b2, WinT, WdecT, bc1, bc2, cst, BG);

    dim3 blk(256);

    // Wc1 = Wenc @ Win  (M=512, N=128, K=512) — matrix cores
    gemm_mfma<0, 1, 64><<<dim3(8, 1), blk, 0, stream>>>(
        WencF, WinT, nullptr, nullptr, nullptr, Wc1, 512, 128, 512);
    // Wc2 = Wout @ Wdec (M=128, N=512, K=512)
    gemm_mfma<0, 1, 64><<<dim3(2, 4), blk, 0, stream>>>(
        WoutF, WdecT, nullptr, nullptr, nullptr, Wc2, 128, 512, 512);

    // skip = x @ Wc1^T + bc1   (K=128, N=512)
    gemm_mfma<0, 1, 64><<<dim3(Mrows / 64, 4), blk, 0, stream>>>(
        XF, Wc1, bc1, nullptr, nullptr, F2, Mrows, Dm, Hin);
    // hn = layernorm(skip)
    layernorm_f16<<<Mrows / 4, 256, 0, stream>>>(F2, ln_g, ln_b, F3);
    // BU = hn @ [B_re;B_im]^T   (K=512, N=1024)
    gemm_mfma<0, 1, 64><<<dim3(Mrows / 64, 8), blk, 0, stream>>>(
        F3, WB, nullptr, nullptr, nullptr, BU, Mrows, 1024, Dm);
    // LinOSS scan (fp32 state)
    scan_phase1<<<Bb * NC, 512, 0, stream>>>(BU, cst, S1);
    scan_phase2<<<(Bb * Dm) / 256, 256, 0, stream>>>(S1, cst, G);
    scan_phase3<<<Bb * NC, 512, 0, stream>>>(BU, cst, G, XS);
    // g = gelu(XS @ WC^T + D*hn)   (K=1024, N=512)
    gemm_mfma<1, 1, 64><<<dim3(Mrows / 64, 4), blk, 0, stream>>>(
        XS, WC, nullptr, F3, Dv, GF, Mrows, Dm, 1024);
    // h2 = skip + (g@w1^T+b1)*sigmoid(g@w2^T+b2)  (interleaved N=1024 -> h2[M,512])
    gemm_mfma<5, 1, 64><<<dim3(Mrows / 64, 8), blk, 0, stream>>>(
        GF, WG, BG, F2, nullptr, F3, Mrows, 1024, Dm);
    // out = h2 @ Wc2^T + bc2   (K=512, N=128, fp32 out)
    gemm_mfma<0, 0, 32><<<dim3(Mrows / 32, 1), blk, 0, stream>>>(
        F3, Wc2, bc2, nullptr, nullptr, (float*)d_out, Mrows, Hin, Dm);
}

// Round 13
// 266.689 us; speedup vs baseline: 1.5029x; 1.0397x over previous
//
#include <hip/hip_runtime.h>
#include <cstddef>
#include <cstdint>
#include <math.h>

typedef _Float16 f16;
typedef f16 f16x8 __attribute__((ext_vector_type(8)));
typedef f16 f16x4 __attribute__((ext_vector_type(4)));
typedef float f32x4 __attribute__((ext_vector_type(4)));

// ---------------- problem constants ----------------
constexpr int Bb   = 8;
constexpr int Ll   = 2048;
constexpr int Hin  = 128;
constexpr int Dm   = 512;
constexpr int Mrows = Bb * Ll;          // 16384
constexpr int NC   = 64;                // scan chunks per sequence
constexpr int CL   = Ll / NC;           // 32 timesteps per chunk
constexpr int SZ1  = Bb * NC * Dm;      // 262144 per state component
constexpr int SD   = 1024;              // interleaved [re|im] row stride

// ---------------- device math helpers ----------------
static __device__ __forceinline__ float sigmoid_f(float x) {
    return 1.f / (1.f + expf(-x));
}
static __device__ __forceinline__ float gelu_tanh_f(float x) {
    float x3 = x * x * x;
    float t  = tanhf(0.7978845608028654f * (x + 0.044715f * x3));
    return 0.5f * x * (1.f + t);
}

// async global->LDS, 16 bytes per lane (linear LDS dest: wave base + lane*16)
static __device__ __forceinline__ void gld16(const f16* g, f16* l) {
    __builtin_amdgcn_global_load_lds(
        (const __attribute__((address_space(1))) void*)g,
        (__attribute__((address_space(3))) void*)l, 16, 0, 0);
}

// hard barrier: real compiler memory fence + HW barrier
static __device__ __forceinline__ void hard_barrier() {
    __builtin_amdgcn_sched_barrier(0);
    asm volatile("s_barrier" ::: "memory");
    __builtin_amdgcn_sched_barrier(0);
}

// ---------------- unified prep kernel ----------------
struct CvtJob { const float* s; f16* d; int n; int lgL; int pitch; int off; int ilv; };
struct CvtJobs { CvtJob j[9]; };

__global__ __launch_bounds__(256) void prep_k(
    CvtJobs jobs,
    const float* __restrict__ Wenc, const float* __restrict__ Win,
    const float* __restrict__ b_in, const float* __restrict__ b_enc,
    const float* __restrict__ Wout, const float* __restrict__ Wdec,
    const float* __restrict__ b_dec, const float* __restrict__ b_out,
    const float* __restrict__ A_diag, const float* __restrict__ log_steps,
    const float* __restrict__ gb1, const float* __restrict__ gb2,
    f16* __restrict__ WinT, f16* __restrict__ WdecT,
    float* __restrict__ bc1, float* __restrict__ bc2,
    float* __restrict__ cst, float* __restrict__ BG)
{
    __shared__ float tile[64][65];
    const int y = blockIdx.y;
    if (y < 9) {
        const CvtJob jb = jobs.j[y];
        const int mask = (1 << jb.lgL) - 1;
        for (int i = (blockIdx.x * 256 + threadIdx.x) * 4; i < jb.n; i += 512 * 256 * 4) {
            const float4 v = *(const float4*)(jb.s + i);
            const int row = i >> jb.lgL;
            const int c   = i & mask;
            f16* dp = jb.ilv
                ? jb.d + (size_t)(((row >> 6) << 7) + (row & 63) + jb.off) * jb.pitch + c
                : jb.d + (size_t)row * jb.pitch + jb.off + c;
            f16x4 o;
            o.x = (f16)v.x; o.y = (f16)v.y; o.z = (f16)v.z; o.w = (f16)v.w;
            *(f16x4*)dp = o;
        }
    } else if (y == 9 || y == 10) {
        // 64x64 tiled transpose-convert
        const int LW   = (y == 9) ? Hin : Dm;
        const float* S = (y == 9) ? Win : Wdec;
        f16* D         = (y == 9) ? WinT : WdecT;
        const int NTIL = (y == 9) ? 16 : 64;
        const int CT   = LW >> 6;
        if (blockIdx.x >= NTIL) return;
        const int tr = blockIdx.x / CT, tc = blockIdx.x % CT;
        const int r0 = tr * 64, c0 = tc * 64;
        const int tid = threadIdx.x;
#pragma unroll
        for (int i = 0; i < 4; ++i) {
            const int r  = (tid >> 4) + i * 16;
            const int c4 = (tid & 15) * 4;
            const float4 v = *(const float4*)(S + (size_t)(r0 + r) * LW + c0 + c4);
            tile[r][c4 + 0] = v.x; tile[r][c4 + 1] = v.y;
            tile[r][c4 + 2] = v.z; tile[r][c4 + 3] = v.w;
        }
        __syncthreads();
#pragma unroll
        for (int i = 0; i < 4; ++i) {
            const int c  = (tid >> 4) + i * 16;
            const int r4 = (tid & 15) * 4;
            f16x4 o;
            o.x = (f16)tile[r4 + 0][c]; o.y = (f16)tile[r4 + 1][c];
            o.z = (f16)tile[r4 + 2][c]; o.w = (f16)tile[r4 + 3][c];
            *(f16x4*)(D + (size_t)(c0 + c) * 512 + r0 + r4) = o;
        }
    } else if (y == 11) {
        const int w    = threadIdx.x >> 6;
        const int lane = threadIdx.x & 63;
        if (blockIdx.x < 128) {
            const int d2 = blockIdx.x * 4 + w;
            const float* wr = Wenc + (size_t)d2 * Dm;
            float p = 0.f;
#pragma unroll
            for (int j = 0; j < 8; ++j)
                p = fmaf(wr[lane + 64 * j], b_in[lane + 64 * j], p);
#pragma unroll
            for (int off = 32; off > 0; off >>= 1) p += __shfl_down(p, off);
            if (lane == 0) bc1[d2] = p + b_enc[d2];
        } else if (blockIdx.x < 160) {
            const int o = (blockIdx.x - 128) * 4 + w;
            const float* wo = Wout + (size_t)o * Dm;
            float p = 0.f;
#pragma unroll
            for (int j = 0; j < 8; ++j)
                p = fmaf(wo[lane + 64 * j], b_dec[lane + 64 * j], p);
#pragma unroll
            for (int off = 32; off > 0; off >>= 1) p += __shfl_down(p, off);
            if (lane == 0) bc2[o] = p + b_out[o];
        }
    } else if (y == 12) {
        const int n = blockIdx.x * 256 + threadIdx.x;
        if (blockIdx.x >= 2 || n >= Dm) return;
        const float a   = fmaxf(A_diag[n], 0.f);
        const float dt  = 1.f / (1.f + expf(-log_steps[n]));
        const float d2a = dt * dt * a;
        const float S   = 1.f / (1.f + d2a);
        const float m11 = 1.f - d2a * S;
        const float m12 = -dt * a * S;
        const float m21 = dt * S;
        const float m22 = S;
        cst[n]            = m11;
        cst[Dm + n]       = m12;
        cst[2 * Dm + n]   = m21;
        cst[3 * Dm + n]   = m22;
        cst[4 * Dm + n]   = m11 * dt;
        cst[5 * Dm + n]   = m21 * dt;
        const int j = n >> 6, loc = n & 63;
        BG[(j << 7) + loc]      = gb1[n];
        BG[(j << 7) + 64 + loc] = gb2[n];
    }
}

// ---------------- fused MFMA GEMM (BMxBN tile, BK=64, counted-vmcnt 2ph) -----
// BN=128: 4 waves in 2x2 (wr,wc).  BN=256: 4 waves, wave w owns cols [w*64,w*64+64).
// KM=0: C = A@W^T + bias
// KM=1: C = gelu( A@W^T + DV[col]*EX[row,col] )
// KM=5: W col-interleaved [w1|w2] per 64; epilogue h2 = EX + (P1+b1)*sigmoid(P2+b2)
template <int KM, int OUTF16, int BM, int BN>
__global__ __launch_bounds__(256, 2) void gemm_mfma(
    const f16* __restrict__ A, const f16* __restrict__ W,
    const float* __restrict__ bias,
    const f16* __restrict__ EX, const float* __restrict__ DV,
    void* __restrict__ Cout, int M, int N, int K)
{
    constexpr int MR   = (BN == 256) ? BM / 16 : BM / 32;  // frag rows per wave
    constexpr int AELE = BM * 64;
    constexpr int BELE = BN * 64;
    constexpr int ACH  = BM * 8 / 256;   // A chunks per thread
    constexpr int BCH  = BN * 8 / 256;   // B chunks per thread
    __shared__ f16 smem[2 * (AELE + BELE)];

    const int tid = threadIdx.x;
    const int l   = tid & 63;
    const int wid = tid >> 6;
    const int lc  = l & 15;
    const int lr  = l >> 4;
    const int row0 = blockIdx.x * BM;
    const int col0 = blockIdx.y * BN;

    const int NT = K >> 6;
    const int swz  = (l & 7) << 4;
    const int off0 = ((lr * 16) ^ swz) >> 1;
    const int off1 = ((64 + lr * 16) ^ swz) >> 1;

    f32x4 acc[MR][4];
#pragma unroll
    for (int i = 0; i < MR; ++i)
#pragma unroll
        for (int j = 0; j < 4; ++j) acc[i][j] = (f32x4){0.f, 0.f, 0.f, 0.f};

    auto stage_a = [&](f16* dst, const f16* src, int rs) {
#pragma unroll
        for (int c = 0; c < ACH; ++c) {
            const int chunk = c * 256 + tid;
            const int row   = chunk >> 3;
            const int kb    = ((chunk & 7) << 4) ^ ((row & 7) << 4);
            gld16(src + (size_t)row * rs + (kb >> 1), dst + chunk * 8);
        }
    };
    auto stage_b = [&](f16* dst, const f16* src, int rs) {
#pragma unroll
        for (int c = 0; c < BCH; ++c) {
            const int chunk = c * 256 + tid;
            const int row   = chunk >> 3;
            const int kb    = ((chunk & 7) << 4) ^ ((row & 7) << 4);
            gld16(src + (size_t)row * rs + (kb >> 1), dst + chunk * 8);
        }
    };
    auto compute = [&](const f16* As, const f16* Bs) {
#pragma unroll
        for (int ks = 0; ks < 2; ++ks) {
            const int off = ks ? off1 : off0;
            f16x8 aF[MR], bF[4];
            if constexpr (BN == 256) {
#pragma unroll
                for (int mi = 0; mi < MR; ++mi)
                    aF[mi] = *(const f16x8*)(As + (mi * 16 + lc) * 64 + off);
#pragma unroll
                for (int ni = 0; ni < 4; ++ni)
                    bF[ni] = *(const f16x8*)(Bs + (wid * 64 + ni * 16 + lc) * 64 + off);
            } else {
                const int wr = wid >> 1, wc = wid & 1;
#pragma unroll
                for (int mi = 0; mi < MR; ++mi)
                    aF[mi] = *(const f16x8*)(As + (wr * (BM / 2) + mi * 16 + lc) * 64 + off);
#pragma unroll
                for (int ni = 0; ni < 4; ++ni)
                    bF[ni] = *(const f16x8*)(Bs + (wc * 64 + ni * 16 + lc) * 64 + off);
            }
#pragma unroll
            for (int mi = 0; mi < MR; ++mi)
#pragma unroll
                for (int ni = 0; ni < 4; ++ni)
                    acc[mi][ni] = __builtin_amdgcn_mfma_f32_16x16x32_f16(
                        aF[mi], bF[ni], acc[mi][ni], 0, 0, 0);
        }
    };

    // ---- counted-vmcnt double-buffered pipeline (fence-hardened) ----
    stage_a(smem, A + (size_t)row0 * K, K);
    stage_b(smem + 2 * AELE, W + (size_t)col0 * K, K);
    int cur = 0;
    for (int kt = 0; kt < NT; ++kt) {
        if (kt + 1 < NT) {
            const int k1 = (kt + 1) << 6;
            stage_a(smem + (cur ^ 1) * AELE, A + (size_t)row0 * K + k1, K);
            stage_b(smem + 2 * AELE + (cur ^ 1) * BELE, W + (size_t)col0 * K + k1, K);
            // wait for the CURRENT tile (oldest ACH+BCH per-thread loads)
            if constexpr (ACH + BCH == 10)     asm volatile("s_waitcnt vmcnt(10)" ::: "memory");
            else if constexpr (ACH + BCH == 6) asm volatile("s_waitcnt vmcnt(6)" ::: "memory");
            else                               asm volatile("s_waitcnt vmcnt(5)" ::: "memory");
        } else {
            asm volatile("s_waitcnt vmcnt(0)" ::: "memory");
        }
        __builtin_amdgcn_sched_barrier(0);
        hard_barrier();                      // current-tile loads landed (all waves)
        compute(smem + cur * AELE, smem + 2 * AELE + cur * BELE);
        hard_barrier();                      // reads of buf[cur] done before overwrite
        cur ^= 1;
    }

    // ---------------- epilogue ----------------
    float* Cf32 = (float*)Cout;
    f16*   Cf16 = (f16*)Cout;
    if constexpr (KM == 5) {
        // GLU combine (BN=256): waves (2g, 2g+1) pair P1/P2 for h-group g
        static_assert(BN == 256, "KM=5 requires BN=256");
        float* sig = (float*)smem;  // [2][BM][65]
        const int grp = wid >> 1;
        const int pg  = wid & 1;
        __syncthreads();
        if (pg == 1) {
#pragma unroll
            for (int mi = 0; mi < MR; ++mi)
#pragma unroll
                for (int ni = 0; ni < 4; ++ni) {
                    const int col = col0 + wid * 64 + ni * 16 + lc;
                    const int rl0 = mi * 16 + lr * 4;
                    const f32x4 v = acc[mi][ni];
#pragma unroll
                    for (int r = 0; r < 4; ++r)
                        sig[(grp * BM + rl0 + r) * 65 + ni * 16 + lc] =
                            sigmoid_f(v[r] + bias[col]);
                }
        }
        __syncthreads();
        if (pg == 0) {
#pragma unroll
            for (int mi = 0; mi < MR; ++mi)
#pragma unroll
                for (int ni = 0; ni < 4; ++ni) {
                    const int cl   = ni * 16 + lc;
                    const int col  = col0 + wid * 64 + cl;           // bias index
                    const int hcol = blockIdx.y * 128 + grp * 64 + cl; // h2 col
                    const int rl0  = mi * 16 + lr * 4;
                    const f32x4 v = acc[mi][ni];
#pragma unroll
                    for (int r = 0; r < 4; ++r) {
                        const int row = row0 + rl0 + r;
                        const float o = (float)EX[(size_t)row * Dm + hcol]
                                      + (v[r] + bias[col]) * sig[(grp * BM + rl0 + r) * 65 + cl];
                        Cf16[(size_t)row * Dm + hcol] = (f16)o;
                    }
                }
        }
        return;
    }
#pragma unroll
    for (int mi = 0; mi < MR; ++mi) {
#pragma unroll
        for (int ni = 0; ni < 4; ++ni) {
            int col, rbase;
            if constexpr (BN == 256) {
                col   = col0 + wid * 64 + ni * 16 + lc;
                rbase = row0 + mi * 16 + lr * 4;
            } else {
                col   = col0 + (wid & 1) * 64 + ni * 16 + lc;
                rbase = row0 + (wid >> 1) * (BM / 2) + mi * 16 + lr * 4;
            }
            const f32x4 v = acc[mi][ni];
            if (KM == 1) {
                const float dv = DV[col];
#pragma unroll
                for (int r = 0; r < 4; ++r) {
                    const size_t idx = (size_t)(rbase + r) * N + col;
                    const float o = gelu_tanh_f(v[r] + dv * (float)EX[idx]);
                    if (OUTF16) Cf16[idx] = (f16)o; else Cf32[idx] = o;
                }
            } else {
                const float bv = bias ? bias[col] : 0.f;
#pragma unroll
                for (int r = 0; r < 4; ++r) {
                    const float o = v[r] + bv;
                    const size_t idx = (size_t)(rbase + r) * N + col;
                    if (OUTF16) Cf16[idx] = (f16)o; else Cf32[idx] = o;
                }
            }
        }
    }
}

// ---------------- LayerNorm (rows of 512, f16 in/out) ----------------
__global__ __launch_bounds__(256) void layernorm_f16(
    const f16* __restrict__ X, const float* __restrict__ g,
    const float* __restrict__ b, f16* __restrict__ Y)
{
    const int lane = threadIdx.x & 63;
    const int w    = threadIdx.x >> 6;
    const int row  = blockIdx.x * 4 + w;
    const size_t base = (size_t)row * Dm + lane * 8;

    const f16x8 v = *(const f16x8*)(X + base);
    float x[8];
    float s = 0.f, q = 0.f;
#pragma unroll
    for (int i = 0; i < 8; ++i) {
        x[i] = (float)v[i];
        s += x[i]; q += x[i] * x[i];
    }
#pragma unroll
    for (int off = 32; off > 0; off >>= 1) {
        s += __shfl_xor(s, off);
        q += __shfl_xor(q, off);
    }
    const float mu  = s * (1.f / 512.f);
    const float var = q * (1.f / 512.f) - mu * mu;
    const float rs  = rsqrtf(var + 1e-5f);

    const float4 g0 = *(const float4*)(g + lane * 8);
    const float4 g1 = *(const float4*)(g + lane * 8 + 4);
    const float4 b0 = *(const float4*)(b + lane * 8);
    const float4 b1 = *(const float4*)(b + lane * 8 + 4);
    const float gg[8] = {g0.x, g0.y, g0.z, g0.w, g1.x, g1.y, g1.z, g1.w};
    const float bb[8] = {b0.x, b0.y, b0.z, b0.w, b1.x, b1.y, b1.z, b1.w};
    f16x8 o;
#pragma unroll
    for (int i = 0; i < 8; ++i)
        o[i] = (f16)((x[i] - mu) * rs * gg[i] + bb[i]);
    *(f16x8*)(Y + base) = o;
}

// ---------------- scan phase 1 (interleaved [re|im] rows of SD) --------------
__global__ __launch_bounds__(512) void scan_phase1(
    const f16* __restrict__ BU, const float* __restrict__ cst,
    float* __restrict__ S1)
{
    const int n = threadIdx.x;
    const int c = blockIdx.x & (NC - 1);
    const int b = blockIdx.x >> 6;
    const float m11 = cst[n],          m12 = cst[Dm + n];
    const float m21 = cst[2 * Dm + n], m22 = cst[3 * Dm + n];
    const float c1  = cst[4 * Dm + n], c2  = cst[5 * Dm + n];

    float zr = 0.f, xr = 0.f, zi = 0.f, xi = 0.f;
    const size_t base = ((size_t)b * Ll + (size_t)c * CL) * SD + n;
#pragma unroll 4
    for (int t = 0; t < CL; ++t) {
        const float br = (float)BU[base + (size_t)t * SD];
        const float bi = (float)BU[base + (size_t)t * SD + 512];
        const float zrn = fmaf(m11, zr, fmaf(m12, xr, c1 * br));
        const float xrn = fmaf(m21, zr, fmaf(m22, xr, c2 * br));
        const float zin = fmaf(m11, zi, fmaf(m12, xi, c1 * bi));
        const float xin = fmaf(m21, zi, fmaf(m22, xi, c2 * bi));
        zr = zrn; xr = xrn; zi = zin; xi = xin;
    }
    const int idx = blockIdx.x * Dm + n;
    S1[idx]            = zr;
    S1[SZ1 + idx]      = xr;
    S1[2 * SZ1 + idx]  = zi;
    S1[3 * SZ1 + idx]  = xi;
}

// ---------------- scan phase 2 ----------------
__global__ __launch_bounds__(256) void scan_phase2(
    const float* __restrict__ S1, const float* __restrict__ cst,
    float* __restrict__ G)
{
    const int gidx = blockIdx.x * 256 + threadIdx.x; // 0..4095
    const int n = gidx & (Dm - 1);
    const int b = gidx >> 9;
    const float m11 = cst[n],          m12 = cst[Dm + n];
    const float m21 = cst[2 * Dm + n], m22 = cst[3 * Dm + n];

    float p11 = 1.f, p12 = 0.f, p21 = 0.f, p22 = 1.f;
    for (int i = 0; i < CL; ++i) {
        const float q11 = m11 * p11 + m12 * p21;
        const float q12 = m11 * p12 + m12 * p22;
        const float q21 = m21 * p11 + m22 * p21;
        const float q22 = m21 * p12 + m22 * p22;
        p11 = q11; p12 = q12; p21 = q21; p22 = q22;
    }

    float gzr = 0.f, gxr = 0.f, gzi = 0.f, gxi = 0.f;
    for (int c = 0; c < NC; ++c) {
        const int idx = (b * NC + c) * Dm + n;
        G[idx]           = gzr;
        G[SZ1 + idx]     = gxr;
        G[2 * SZ1 + idx] = gzi;
        G[3 * SZ1 + idx] = gxi;
        const float szr = S1[idx],           sxr = S1[SZ1 + idx];
        const float szi = S1[2 * SZ1 + idx], sxi = S1[3 * SZ1 + idx];
        const float t1 = p11 * gzr + p12 * gxr + szr;
        const float t2 = p21 * gzr + p22 * gxr + sxr;
        const float t3 = p11 * gzi + p12 * gxi + szi;
        const float t4 = p21 * gzi + p22 * gxi + sxi;
        gzr = t1; gxr = t2; gzi = t3; gxi = t4;
    }
}

// ---------------- scan phase 3: re-scan; XS = [xr | -xi] interleaved ---------
__global__ __launch_bounds__(512) void scan_phase3(
    const f16* __restrict__ BU, const float* __restrict__ cst,
    const float* __restrict__ G, f16* __restrict__ XS)
{
    const int n = threadIdx.x;
    const int c = blockIdx.x & (NC - 1);
    const int b = blockIdx.x >> 6;
    const float m11 = cst[n],          m12 = cst[Dm + n];
    const float m21 = cst[2 * Dm + n], m22 = cst[3 * Dm + n];
    const float c1  = cst[4 * Dm + n], c2  = cst[5 * Dm + n];

    const int sidx = blockIdx.x * Dm + n;
    float zr = G[sidx];
    float xr = G[SZ1 + sidx];
    float zi = G[2 * SZ1 + sidx];
    float xi = G[3 * SZ1 + sidx];

    const size_t base = ((size_t)b * Ll + (size_t)c * CL) * SD + n;
#pragma unroll 4
    for (int t = 0; t < CL; ++t) {
        const float br = (float)BU[base + (size_t)t * SD];
        const float bi = (float)BU[base + (size_t)t * SD + 512];
        const float zrn = fmaf(m11, zr, fmaf(m12, xr, c1 * br));
        const float xrn = fmaf(m21, zr, fmaf(m22, xr, c2 * br));
        const float zin = fmaf(m11, zi, fmaf(m12, xi, c1 * bi));
        const float xin = fmaf(m21, zi, fmaf(m22, xi, c2 * bi));
        zr = zrn; xr = xrn; zi = zin; xi = xin;
        XS[base + (size_t)t * SD]       = (f16)xr;
        XS[base + (size_t)t * SD + 512] = (f16)(-xi);
    }
}

// ---------------- launch ----------------
extern "C" void kernel_launch(void* const* d_in, const int* in_sizes, int n_in,
                              void* d_out, int out_size, void* d_ws, size_t ws_size,
                              hipStream_t stream)
{
    const float* x         = (const float*)d_in[0];
    const float* W_in      = (const float*)d_in[1];
    const float* b_in      = (const float*)d_in[2];
    const float* W_enc     = (const float*)d_in[3];
    const float* b_enc     = (const float*)d_in[4];
    const float* ln_g      = (const float*)d_in[5];
    const float* ln_b      = (const float*)d_in[6];
    const float* A_diag    = (const float*)d_in[7];
    const float* log_steps = (const float*)d_in[8];
    const float* B_re      = (const float*)d_in[9];
    const float* B_im      = (const float*)d_in[10];
    const float* C_re      = (const float*)d_in[11];
    const float* C_im      = (const float*)d_in[12];
    const float* Dv        = (const float*)d_in[13];
    const float* glu_w1    = (const float*)d_in[14];
    const float* glu_b1    = (const float*)d_in[15];
    const float* glu_w2    = (const float*)d_in[16];
    const float* glu_b2    = (const float*)d_in[17];
    const float* W_dec     = (const float*)d_in[18];
    const float* b_dec     = (const float*)d_in[19];
    const float* W_out     = (const float*)d_in[20];
    const float* b_out     = (const float*)d_in[21];

    char* ws = (char*)d_ws;
    const size_t MB = 1 << 20;
    const size_t KB = 1 << 10;
    f16*   F2  = (f16*)(ws);             // skip f16 [M,512]
    f16*   F3  = (f16*)(ws + 16 * MB);   // hn f16 [M,512]; later h2
    f16*   XS  = (f16*)(ws + 32 * MB);   // [M,1024] = [xr | -xi]
    f16*   BU  = (f16*)(ws + 64 * MB);   // [M,1024] = [BuR | BuI]
    f16*   GF  = (f16*)(ws + 96 * MB);   // g f16 [M,512]
    f16*   XF  = (f16*)(ws + 112 * MB);  // x f16 [M,128] (4 MB)
    float* S1  = (float*)(ws + 116 * MB);           // 4 MB (NC=64)
    float* G   = (float*)(ws + 120 * MB);           // 4 MB
    float* cst = (float*)(ws + 124 * MB);
    float* BG  = (float*)(ws + 124 * MB + 64 * KB); // interleaved [b1|b2]
    float* bc1 = (float*)(ws + 124 * MB + 128 * KB);
    float* bc2 = (float*)(ws + 124 * MB + 192 * KB);
    f16*   WB  = (f16*)(ws + 125 * MB);  // [1024][512] = [B_re; B_im]
    f16*   WC  = (f16*)(ws + 126 * MB);  // [512][1024] = [C_re | C_im]
    f16*   WG  = (f16*)(ws + 127 * MB);  // [1024][512] = interleaved [w1|w2] per 64
    f16*   Wc1   = (f16*)(ws + 128 * MB);             // [512][128]
    f16*   Wc2   = (f16*)(ws + 128 * MB + 128 * KB);  // [128][512]
    f16*   WinT  = (f16*)(ws + 128 * MB + 256 * KB);  // [128][512]
    f16*   WoutF = (f16*)(ws + 128 * MB + 384 * KB);  // [128][512]
    f16*   WencF = (f16*)(ws + 128 * MB + 512 * KB);  // [512][512]
    f16*   WdecT = (f16*)(ws + 129 * MB);             // [512][512]

    CvtJobs jobs;
    jobs.j[0] = {x,      XF,            Mrows * Hin, 7, Hin,  0,   0};
    jobs.j[1] = {B_re,   WB,            Dm * Dm,     9, Dm,   0,   0};
    jobs.j[2] = {B_im,   WB + 512 * Dm, Dm * Dm,     9, Dm,   0,   0};
    jobs.j[3] = {C_re,   WC,            Dm * Dm,     9, 1024, 0,   0};
    jobs.j[4] = {C_im,   WC,            Dm * Dm,     9, 1024, 512, 0};
    jobs.j[5] = {glu_w1, WG,            Dm * Dm,     9, Dm,   0,   1};
    jobs.j[6] = {glu_w2, WG,            Dm * Dm,     9, Dm,   64,  1};
    jobs.j[7] = {W_enc,  WencF,         Dm * Dm,     9, Dm,   0,   0};
    jobs.j[8] = {W_out,  WoutF,         Hin * Dm,    9, Dm,   0,   0};

    prep_k<<<dim3(512, 13), 256, 0, stream>>>(
        jobs, W_enc, W_in, b_in, b_enc, W_out, W_dec, b_dec, b_out,
        A_diag, log_steps, glu_b1, glu_b2, WinT, WdecT, bc1, bc2, cst, BG);

    dim3 blk(256);

    // Wc1 = Wenc @ Win  (M=512, N=128, K=512)
    gemm_mfma<0, 1, 64, 128><<<dim3(8, 1), blk, 0, stream>>>(
        WencF, WinT, nullptr, nullptr, nullptr, Wc1, 512, 128, 512);
    // Wc2 = Wout @ Wdec (M=128, N=512, K=512)
    gemm_mfma<0, 1, 64, 128><<<dim3(2, 4), blk, 0, stream>>>(
        WoutF, WdecT, nullptr, nullptr, nullptr, Wc2, 128, 512, 512);

    // skip = x @ Wc1^T + bc1   (K=128, N=512)
    gemm_mfma<0, 1, 64, 256><<<dim3(Mrows / 64, 2), blk, 0, stream>>>(
        XF, Wc1, bc1, nullptr, nullptr, F2, Mrows, Dm, Hin);
    // hn = layernorm(skip)
    layernorm_f16<<<Mrows / 4, 256, 0, stream>>>(F2, ln_g, ln_b, F3);
    // BU = hn @ [B_re;B_im]^T   (K=512, N=1024)
    gemm_mfma<0, 1, 64, 256><<<dim3(Mrows / 64, 4), blk, 0, stream>>>(
        F3, WB, nullptr, nullptr, nullptr, BU, Mrows, 1024, Dm);
    // LinOSS scan (fp32 state)
    scan_phase1<<<Bb * NC, 512, 0, stream>>>(BU, cst, S1);
    scan_phase2<<<(Bb * Dm) / 256, 256, 0, stream>>>(S1, cst, G);
    scan_phase3<<<Bb * NC, 512, 0, stream>>>(BU, cst, G, XS);
    // g = gelu(XS @ WC^T + D*hn)   (K=1024, N=512)
    gemm_mfma<1, 1, 64, 256><<<dim3(Mrows / 64, 2), blk, 0, stream>>>(
        XS, WC, nullptr, F3, Dv, GF, Mrows, Dm, 1024);
    // h2 = skip + (g@w1^T+b1)*sigmoid(g@w2^T+b2)  (interleaved N=1024 -> h2[M,512])
    gemm_mfma<5, 1, 64, 256><<<dim3(Mrows / 64, 4), blk, 0, stream>>>(
        GF, WG, BG, F2, nullptr, F3, Mrows, 1024, Dm);
    // out = h2 @ Wc2^T + bc2   (K=512, N=128, fp32 out)
    gemm_mfma<0, 0, 32, 128><<<dim3(Mrows / 32, 1), blk, 0, stream>>>(
        F3, Wc2, bc2, nullptr, nullptr, (float*)d_out, Mrows, Hin, Dm);
}